// Round 15
// baseline (2191.173 us; speedup 1.0000x reference)
//
#include <hip/hip_runtime.h>
#include <hip/hip_bf16.h>

#define NB 16
#define NN 4096
#define NS 1024
#define NK 32
#define CF 64
#define CIN 67
#define MTOT 524288          // NB*NS*NK
#define NEWP_OFF 49152       // NB*NS*3

__device__ inline void stY(float* p, float v) { *p = v; }
__device__ inline void stY(__hip_bfloat16* p, float v) { *p = __float2bfloat16(v); }
__device__ inline float ldY(const float* p) { return *p; }
__device__ inline float ldY(const __hip_bfloat16* p) { return __bfloat162float(*p); }
__device__ inline float4 ldY4(const float* p) { return *(const float4*)p; }
__device__ inline float4 ldY4(const __hip_bfloat16* p) {
    return make_float4(ldY(p), ldY(p + 1), ldY(p + 2), ldY(p + 3));
}
__device__ inline void stY4(float* p, float4 v) { *(float4*)p = v; }
__device__ inline void stY4(__hip_bfloat16* p, float4 v) {
    stY(p, v.x); stY(p + 1, v.y); stY(p + 2, v.z); stY(p + 3, v.w);
}

// ---- DPP reduce helpers (ctrl must be ICE -> template) -------------------------
template <int CTRL>
__device__ inline float dppredmax(float v) {
    int j = __builtin_amdgcn_update_dpp(__float_as_int(v), __float_as_int(v),
                                        CTRL, 0xF, 0xF, false);
    return fmaxf(v, __int_as_float(j));
}
template <int CTRL>
__device__ inline float dppredmin(float v) {
    int j = __builtin_amdgcn_update_dpp(__float_as_int(v), __float_as_int(v),
                                        CTRL, 0xF, 0xF, false);
    return fminf(v, __int_as_float(j));
}
template <int CTRL>
__device__ inline float dppadd0(float v) {   // bound_ctrl=1: invalid lanes read 0
    int j = __builtin_amdgcn_update_dpp(0, __float_as_int(v), CTRL, 0xF, 0xF, true);
    return __fadd_rn(v, __int_as_float(j));
}
template <int CTRL>
__device__ inline unsigned long long dppredmin64(unsigned long long v) {
    int lo = (int)(unsigned)(v & 0xffffffffULL), hi = (int)(unsigned)(v >> 32);
    unsigned nlo = (unsigned)__builtin_amdgcn_update_dpp(lo, lo, CTRL, 0xF, 0xF, false);
    unsigned nhi = (unsigned)__builtin_amdgcn_update_dpp(hi, hi, CTRL, 0xF, 0xF, false);
    unsigned long long o = ((unsigned long long)nhi << 32) | nlo;
    return o < v ? o : v;
}
__device__ inline float wavemax_to_all(float tmax) {
    float g = tmax;
    g = dppredmax<0x111>(g);   // row_shr:1
    g = dppredmax<0x112>(g);   // row_shr:2
    g = dppredmax<0x114>(g);   // row_shr:4
    g = dppredmax<0x118>(g);   // row_shr:8
    g = dppredmax<0x142>(g);   // row_bcast15
    g = dppredmax<0x143>(g);   // row_bcast31 -> lane 63 = wave max
    return __int_as_float(__builtin_amdgcn_readlane(__float_as_int(g), 63));
}
__device__ inline unsigned long long wavemin64_to_all(unsigned long long v) {
    v = dppredmin64<0x111>(v);
    v = dppredmin64<0x112>(v);
    v = dppredmin64<0x114>(v);
    v = dppredmin64<0x118>(v);
    v = dppredmin64<0x142>(v);
    v = dppredmin64<0x143>(v);
    unsigned lo = (unsigned)__builtin_amdgcn_readlane((int)(unsigned)(v & 0xffffffffULL), 63);
    unsigned hi = (unsigned)__builtin_amdgcn_readlane((int)(unsigned)(v >> 32), 63);
    return ((unsigned long long)hi << 32) | lo;
}
__device__ inline float segsum16(float v) {    // lanes 15,31,47,63 hold 16-seg sum
    v = dppadd0<0x111>(v); v = dppadd0<0x112>(v);
    v = dppadd0<0x114>(v); v = dppadd0<0x118>(v);
    return v;
}
__device__ inline float segsum32(float v) {    // lanes 31,63 hold 32-seg sum
    v = segsum16(v); v = dppadd0<0x142>(v);
    return v;
}
__device__ inline float quadmax(float v) {     // all 4 lanes of quad hold max
    v = dppredmax<0xB1>(v); v = dppredmax<0x4E>(v);
    return v;
}
__device__ inline float quadmin(float v) {
    v = dppredmin<0xB1>(v); v = dppredmin<0x4E>(v);
    return v;
}

// -------- FPS (round-6 proven, 594us): cpt LDS + all-DPP max + u64 part --------
__global__ __launch_bounds__(256) void fps_kernel(const float* __restrict__ xyz,
                                                  int* __restrict__ fps_idx) {
    __shared__ float4 cpt[NN];                  // 64 KiB packed coords
    __shared__ unsigned long long part[2][4];
    const int b = blockIdx.x, t = threadIdx.x;
    const float4* src = (const float4*)(xyz + (size_t)b * NN * 3);
    float px[16], py[16], pz[16], dist[16];
#pragma unroll
    for (int j = 0; j < 4; ++j) {
        float4 A = src[t * 12 + 3 * j], B4 = src[t * 12 + 3 * j + 1], C4 = src[t * 12 + 3 * j + 2];
        px[4 * j + 0] = A.x;  py[4 * j + 0] = A.y;  pz[4 * j + 0] = A.z;
        px[4 * j + 1] = A.w;  py[4 * j + 1] = B4.x; pz[4 * j + 1] = B4.y;
        px[4 * j + 2] = B4.z; py[4 * j + 2] = B4.w; pz[4 * j + 2] = C4.x;
        px[4 * j + 3] = C4.y; py[4 * j + 3] = C4.z; pz[4 * j + 3] = C4.w;
    }
#pragma unroll
    for (int i = 0; i < 16; ++i) {
        dist[i] = 1e10f;
        cpt[16 * t + i] = make_float4(px[i], py[i], pz[i], 0.f);
    }
    __syncthreads();
    int cur = 0;
    float4 c = cpt[0];
    const int wv = t >> 6;
    for (int s = 0; s < NS; ++s) {
        if (t == 0) fps_idx[(b << 10) + s] = cur;
#pragma unroll
        for (int i = 0; i < 16; ++i) {
            float dx = __fsub_rn(px[i], c.x), dy = __fsub_rn(py[i], c.y), dz = __fsub_rn(pz[i], c.z);
            float d = __fadd_rn(__fadd_rn(__fmul_rn(dx, dx), __fmul_rn(dy, dy)), __fmul_rn(dz, dz));
            dist[i] = fminf(dist[i], d);
        }
        float m0 = fmaxf(dist[0], dist[1]),   m1 = fmaxf(dist[2], dist[3]);
        float m2 = fmaxf(dist[4], dist[5]),   m3 = fmaxf(dist[6], dist[7]);
        float m4 = fmaxf(dist[8], dist[9]),   m5 = fmaxf(dist[10], dist[11]);
        float m6 = fmaxf(dist[12], dist[13]), m7 = fmaxf(dist[14], dist[15]);
        m0 = fmaxf(m0, m1); m2 = fmaxf(m2, m3); m4 = fmaxf(m4, m5); m6 = fmaxf(m6, m7);
        m0 = fmaxf(m0, m2); m4 = fmaxf(m4, m6);
        const float tmax = fmaxf(m0, m4);
        int mi = 15;
#pragma unroll
        for (int i = 14; i >= 0; --i) mi = (dist[i] == tmax) ? i : mi;
        const float gmax = wavemax_to_all(tmax);
        unsigned long long mask = __ballot(tmax == gmax);
        int ldr = __ffsll(mask) - 1;
        int widx = __builtin_amdgcn_readlane(16 * t + mi, ldr);
        if ((t & 63) == 0) {
            part[s & 1][wv] =
                ((unsigned long long)__float_as_uint(gmax) << 32) | (unsigned)(4095 - widx);
        }
        __syncthreads();
        unsigned long long k0 = part[s & 1][0], k1 = part[s & 1][1];
        unsigned long long k2 = part[s & 1][2], k3 = part[s & 1][3];
        unsigned long long ka = k0 > k1 ? k0 : k1, kb = k2 > k3 ? k2 : k3;
        unsigned long long k = ka > kb ? ka : kb;
        cur = 4095 - (int)(unsigned)(k & 0xffffffffu);
        c = cpt[cur];
    }
}

// ---------------- kNN: wave-private top-32, all-DPP u64 min extraction ----------
__global__ __launch_bounds__(256) void knn_kernel(const float* __restrict__ xyz,
                                                  const int* __restrict__ fps_idx,
                                                  int* __restrict__ knn,
                                                  float* __restrict__ out) {
    __shared__ float4 cpt[NN];                  // {x,y,z,|p|^2}
    const int b = blockIdx.x >> 5, cb = blockIdx.x & 31, t = threadIdx.x;
    for (int p = t; p < NN; p += 256) {
        const float* xr = xyz + ((size_t)(b << 12) + p) * 3;
        float x = xr[0], y = xr[1], z = xr[2];
        float pn = __fadd_rn(__fadd_rn(__fmul_rn(x, x), __fmul_rn(y, y)), __fmul_rn(z, z));
        cpt[p] = make_float4(x, y, z, pn);
    }
    __syncthreads();
    const int lane = t & 63, wv = t >> 6;
    for (int r = 0; r < 8; ++r) {
        const int s = (cb << 5) + (wv << 3) + r;
        const int ci = fps_idx[(b << 10) + s];
        const float4 cq = cpt[ci];
        const float cx = cq.x, cy = cq.y, cz = cq.z, cn = cq.w;
        if (lane < 3) out[((size_t)(b << 10) + s) * 3 + lane] = (lane == 0) ? cx : (lane == 1 ? cy : cz);
        unsigned long long m1 = ~0ULL, m2 = ~0ULL, m3 = ~0ULL;
#pragma unroll
        for (int i = 0; i < 64; ++i) {
            int p = lane + (i << 6);
            float4 q = cpt[p];
            float dot = __fadd_rn(__fadd_rn(__fmul_rn(cx, q.x), __fmul_rn(cy, q.y)),
                                  __fmul_rn(cz, q.z));
            float d2 = __fsub_rn(__fadd_rn(cn, q.w), __fmul_rn(2.0f, dot));
            unsigned u = __float_as_uint(d2);
            unsigned enc = u ^ ((unsigned)((int)u >> 31) | 0x80000000u);
            unsigned long long key = ((unsigned long long)enc << 32) | (unsigned)p;
            if (key < m3) {
                if (key < m1)      { m3 = m2; m2 = m1; m1 = key; }
                else if (key < m2) { m3 = m2; m2 = key; }
                else               { m3 = key; }
            }
        }
        unsigned myidx = 0;
        for (int j = 0; j < 32; ++j) {
            const unsigned long long vmin = wavemin64_to_all(m1);
            if (lane == j) myidx = (unsigned)(vmin & 0xffffffffu);
            if (m1 == vmin) {
                m1 = m2; m2 = m3; m3 = ~0ULL;
                if (m1 == ~0ULL) {
#pragma unroll
                    for (int i = 0; i < 64; ++i) {
                        int p = lane + (i << 6);
                        float4 q = cpt[p];
                        float dot = __fadd_rn(__fadd_rn(__fmul_rn(cx, q.x), __fmul_rn(cy, q.y)),
                                              __fmul_rn(cz, q.z));
                        float d2 = __fsub_rn(__fadd_rn(cn, q.w), __fmul_rn(2.0f, dot));
                        unsigned u = __float_as_uint(d2);
                        unsigned enc = u ^ ((unsigned)((int)u >> 31) | 0x80000000u);
                        unsigned long long key = ((unsigned long long)enc << 32) | (unsigned)p;
                        if (key > vmin && key < m3) {
                            if (key < m1)      { m3 = m2; m2 = m1; m1 = key; }
                            else if (key < m2) { m3 = m2; m2 = key; }
                            else               { m3 = key; }
                        }
                    }
                }
            }
        }
        const int rowbase = ((b << 10) + s) << 5;
        if (lane < 32) knn[rowbase + lane] = (int)myidx;
    }
}

// ------ conv0: tiled GEMM. TILE_E=128, C=67, O=64. thread: 4 elem x 8 out -------
template <typename YT>
__global__ __launch_bounds__(256) void conv0_kernel(
    const float* __restrict__ xyz, const float* __restrict__ points,
    const float* __restrict__ out_xyz, const int* __restrict__ knn,
    const float* __restrict__ w0, const float* __restrict__ b0,
    YT* __restrict__ Y0, float* __restrict__ gs, float* __restrict__ gq) {
    __shared__ float Ht[CIN][128];
    __shared__ float Wt[CIN][64];
    __shared__ float bsm[64], bqm[64];
    const int t = threadIdx.x;
    const int eb = blockIdx.x << 7;
    for (int i = t; i < CIN * 64; i += 256) {
        int c = i >> 6, o = i & 63;
        Wt[c][o] = w0[o * CIN + c];
    }
    {
        const int le = t >> 1, part = t & 1;
        const int e = eb + le;
        const int b = e >> 15, s = (e >> 5) & 1023;
        const int pidx = knn[e];
        const float4* pr = (const float4*)(points + (((size_t)(b << 12) + pidx) << 6)) + (part << 3);
        if (part == 0) {
            const float* xr = xyz + ((size_t)(b << 12) + pidx) * 3;
            const float* cr = out_xyz + ((size_t)(b << 10) + s) * 3;
            Ht[0][le] = xr[0] - cr[0];
            Ht[1][le] = xr[1] - cr[1];
            Ht[2][le] = xr[2] - cr[2];
        }
#pragma unroll
        for (int q = 0; q < 8; ++q) {
            float4 v = pr[q];
            int c = 3 + (part << 5) + (q << 2);
            Ht[c][le] = v.x; Ht[c + 1][le] = v.y; Ht[c + 2][le] = v.z; Ht[c + 3][le] = v.w;
        }
    }
    __syncthreads();
    const int te = t & 31, to = t >> 5;
    float acc[4][8];
#pragma unroll
    for (int j = 0; j < 4; ++j)
#pragma unroll
        for (int i = 0; i < 8; ++i) acc[j][i] = 0.f;
#pragma unroll 2
    for (int c = 0; c < CIN; ++c) {
        const float4 a0 = *(const float4*)&Ht[c][te << 2];
        const float4 wa = *(const float4*)&Wt[c][to << 3];
        const float4 wb = *(const float4*)&Wt[c][(to << 3) + 4];
        const float av[4] = {a0.x, a0.y, a0.z, a0.w};
        const float wvv[8] = {wa.x, wa.y, wa.z, wa.w, wb.x, wb.y, wb.z, wb.w};
#pragma unroll
        for (int j = 0; j < 4; ++j)
#pragma unroll
            for (int i = 0; i < 8; ++i) acc[j][i] += av[j] * wvv[i];
    }
    const int o0 = to << 3;
    float s1v[8], s2v[8];
#pragma unroll
    for (int i = 0; i < 8; ++i) {
        const float bi = b0[o0 + i];
        float ss = 0.f, qq = 0.f;
#pragma unroll
        for (int j = 0; j < 4; ++j) {
            float v = acc[j][i] + bi;
            acc[j][i] = v;
            ss += v; qq += v * v;
        }
        s1v[i] = ss; s2v[i] = qq;
    }
#pragma unroll
    for (int i = 0; i < 8; ++i) {
        const size_t base = (size_t)(o0 + i) * MTOT + eb + (te << 2);
        stY4(&Y0[base], make_float4(acc[0][i], acc[1][i], acc[2][i], acc[3][i]));
    }
#pragma unroll
    for (int i = 0; i < 8; ++i) { s1v[i] = segsum32(s1v[i]); s2v[i] = segsum32(s2v[i]); }
    if ((t & 31) == 31) {
#pragma unroll
        for (int i = 0; i < 8; ++i) { bsm[o0 + i] = s1v[i]; bqm[o0 + i] = s2v[i]; }
    }
    __syncthreads();
    if (t < 64) atomicAdd(&gs[t], bsm[t]);
    else if (t < 128) atomicAdd(&gq[t - 64], bqm[t - 64]);
}

// ------ conv1: tiled GEMM + in-block BN0 finalize. thread: 8 elem x 4 out -------
template <typename YT>
__global__ __launch_bounds__(256) void conv1_kernel(
    const YT* __restrict__ Y0, const float* __restrict__ w1, const float* __restrict__ b1,
    const float* __restrict__ gsp, const float* __restrict__ gqp,
    const float* __restrict__ g, const float* __restrict__ bb,
    YT* __restrict__ Y1, float* __restrict__ gs, float* __restrict__ gq) {
    __shared__ float At[64][128];
    __shared__ float Wt[64][64];
    __shared__ float bnsc[64], bnsh[64];
    __shared__ float bsm[64], bqm[64];
    const int t = threadIdx.x;
    const int eb = blockIdx.x << 7;
    if (t < 64) {
        const float inv = 1.f / (float)MTOT;
        float mean = gsp[t] * inv;
        float var = gqp[t] * inv - mean * mean;
        float r = g[t] / sqrtf(var + 1e-5f);
        bnsc[t] = r; bnsh[t] = bb[t] - mean * r;
    }
    for (int i = t; i < 4096; i += 256) {
        int c = i >> 6, o = i & 63;
        Wt[c][o] = w1[o * 64 + c];
    }
    __syncthreads();
#pragma unroll
    for (int r = 0; r < 8; ++r) {
        int L = (r << 8) + t;                 // float4 id
        int c = L >> 5, col = (L & 31) << 2;
        float4 y = ldY4(&Y0[(size_t)c * MTOT + eb + col]);
        float sx = bnsc[c], hx = bnsh[c];
        At[c][col]     = fmaxf(sx * y.x + hx, 0.f);
        At[c][col + 1] = fmaxf(sx * y.y + hx, 0.f);
        At[c][col + 2] = fmaxf(sx * y.z + hx, 0.f);
        At[c][col + 3] = fmaxf(sx * y.w + hx, 0.f);
    }
    __syncthreads();
    const int te = t & 15, to = t >> 4;
    float acc[8][4];
#pragma unroll
    for (int j = 0; j < 8; ++j)
#pragma unroll
        for (int i = 0; i < 4; ++i) acc[j][i] = 0.f;
#pragma unroll 2
    for (int c = 0; c < 64; ++c) {
        const float4 a0 = *(const float4*)&At[c][te << 3];
        const float4 a1 = *(const float4*)&At[c][(te << 3) + 4];
        const float4 wa = *(const float4*)&Wt[c][to << 2];
        const float av[8] = {a0.x, a0.y, a0.z, a0.w, a1.x, a1.y, a1.z, a1.w};
        const float wvv[4] = {wa.x, wa.y, wa.z, wa.w};
#pragma unroll
        for (int j = 0; j < 8; ++j)
#pragma unroll
            for (int i = 0; i < 4; ++i) acc[j][i] += av[j] * wvv[i];
    }
    const int o0 = to << 2;
    float s1v[4], s2v[4];
#pragma unroll
    for (int i = 0; i < 4; ++i) {
        const float bi = b1[o0 + i];
        float ss = 0.f, qq = 0.f;
#pragma unroll
        for (int j = 0; j < 8; ++j) {
            float v = acc[j][i] + bi;
            acc[j][i] = v;
            ss += v; qq += v * v;
        }
        s1v[i] = ss; s2v[i] = qq;
    }
#pragma unroll
    for (int i = 0; i < 4; ++i) {
        const size_t base = (size_t)(o0 + i) * MTOT + eb + (te << 3);
        stY4(&Y1[base],     make_float4(acc[0][i], acc[1][i], acc[2][i], acc[3][i]));
        stY4(&Y1[base + 4], make_float4(acc[4][i], acc[5][i], acc[6][i], acc[7][i]));
    }
#pragma unroll
    for (int i = 0; i < 4; ++i) { s1v[i] = segsum16(s1v[i]); s2v[i] = segsum16(s2v[i]); }
    if ((t & 15) == 15) {
#pragma unroll
        for (int i = 0; i < 4; ++i) { bsm[o0 + i] = s1v[i]; bqm[o0 + i] = s2v[i]; }
    }
    __syncthreads();
    if (t < 64) atomicAdd(&gs[t], bsm[t]);
    else if (t < 128) atomicAdd(&gq[t - 64], bqm[t - 64]);
}

// ------ conv2s: tiled GEMM + in-block BN1 finalize. thread: 8 elem x 8 out ------
template <typename YT>
__global__ __launch_bounds__(256) void conv2s_kernel(
    const YT* __restrict__ Y1, const float* __restrict__ w2, const float* __restrict__ b2,
    const float* __restrict__ gsp, const float* __restrict__ gqp,
    const float* __restrict__ g, const float* __restrict__ bb,
    float* __restrict__ gs, float* __restrict__ gq,
    float* __restrict__ Mx, float* __restrict__ Mn) {
    __shared__ float At[64][128];
    __shared__ float Wt[64][128];
    __shared__ float bnsc[64], bnsh[64];
    __shared__ float bsm[128], bqm[128];
    __shared__ float mxs[4][128], mns[4][128];
    const int t = threadIdx.x;
    const int eb = blockIdx.x << 7;
    if (t < 64) {
        const float inv = 1.f / (float)MTOT;
        float mean = gsp[t] * inv;
        float var = gqp[t] * inv - mean * mean;
        float r = g[t] / sqrtf(var + 1e-5f);
        bnsc[t] = r; bnsh[t] = bb[t] - mean * r;
    }
    for (int i = t; i < 8192; i += 256) {
        int o = i & 127, c = i >> 7;
        Wt[c][o] = w2[o * 64 + c];
    }
    __syncthreads();
#pragma unroll
    for (int r = 0; r < 8; ++r) {
        int L = (r << 8) + t;
        int c = L >> 5, col = (L & 31) << 2;
        float4 y = ldY4(&Y1[(size_t)c * MTOT + eb + col]);
        float sx = bnsc[c], hx = bnsh[c];
        At[c][col]     = fmaxf(sx * y.x + hx, 0.f);
        At[c][col + 1] = fmaxf(sx * y.y + hx, 0.f);
        At[c][col + 2] = fmaxf(sx * y.z + hx, 0.f);
        At[c][col + 3] = fmaxf(sx * y.w + hx, 0.f);
    }
    __syncthreads();
    const int te = t & 15, to = t >> 4;
    float acc[8][8];
#pragma unroll
    for (int j = 0; j < 8; ++j)
#pragma unroll
        for (int i = 0; i < 8; ++i) acc[j][i] = 0.f;
#pragma unroll 2
    for (int c = 0; c < 64; ++c) {
        const float4 a0 = *(const float4*)&At[c][te << 3];
        const float4 a1 = *(const float4*)&At[c][(te << 3) + 4];
        const float4 wa = *(const float4*)&Wt[c][to << 3];
        const float4 wb = *(const float4*)&Wt[c][(to << 3) + 4];
        const float av[8] = {a0.x, a0.y, a0.z, a0.w, a1.x, a1.y, a1.z, a1.w};
        const float wvv[8] = {wa.x, wa.y, wa.z, wa.w, wb.x, wb.y, wb.z, wb.w};
#pragma unroll
        for (int j = 0; j < 8; ++j)
#pragma unroll
            for (int i = 0; i < 8; ++i) acc[j][i] += av[j] * wvv[i];
    }
    const int o0 = to << 3;
    float s1v[8], s2v[8], mxv[8], mnv[8];
#pragma unroll
    for (int i = 0; i < 8; ++i) {
        const float bi = b2[o0 + i];
        float ss = 0.f, qq = 0.f;
        float mx = -3.4e38f, mn = 3.4e38f;
#pragma unroll
        for (int j = 0; j < 8; ++j) {
            float v = acc[j][i] + bi;
            ss += v; qq += v * v;
            mx = fmaxf(mx, v); mn = fminf(mn, v);
        }
        s1v[i] = ss; s2v[i] = qq; mxv[i] = mx; mnv[i] = mn;
    }
#pragma unroll
    for (int i = 0; i < 8; ++i) {
        s1v[i] = segsum16(s1v[i]); s2v[i] = segsum16(s2v[i]);
        mxv[i] = quadmax(mxv[i]);  mnv[i] = quadmin(mnv[i]);
    }
    if ((t & 15) == 15) {
#pragma unroll
        for (int i = 0; i < 8; ++i) { bsm[o0 + i] = s1v[i]; bqm[o0 + i] = s2v[i]; }
    }
    if ((t & 3) == 0) {
        const int srow = (t & 15) >> 2;
#pragma unroll
        for (int i = 0; i < 8; ++i) { mxs[srow][o0 + i] = mxv[i]; mns[srow][o0 + i] = mnv[i]; }
    }
    __syncthreads();
    if (t < 128) atomicAdd(&gs[t], bsm[t]);
    else atomicAdd(&gq[t - 128], bqm[t - 128]);
    const int sidx0 = blockIdx.x << 2;
    for (int i = t; i < 512; i += 256) {
        int row = i >> 7, o = i & 127;
        Mx[(size_t)(sidx0 + row) * 128 + o] = mxs[row][o];
        Mn[(size_t)(sidx0 + row) * 128 + o] = mns[row][o];
    }
}

// ------- final2: in-block BN2 finalize + relu on extreme over k + transpose -----
__global__ __launch_bounds__(256) void final2_kernel(
    const float* __restrict__ Mx, const float* __restrict__ Mn,
    const float* __restrict__ gsp, const float* __restrict__ gqp,
    const float* __restrict__ g, const float* __restrict__ bb,
    float* __restrict__ out) {
    __shared__ float T[128][65];
    __shared__ float bnsc[128], bnsh[128];
    const int t = threadIdx.x;
    if (t < 128) {
        const float inv = 1.f / (float)MTOT;
        float mean = gsp[t] * inv;
        float var = gqp[t] * inv - mean * mean;
        float r = g[t] / sqrtf(var + 1e-5f);
        bnsc[t] = r; bnsh[t] = bb[t] - mean * r;
    }
    __syncthreads();
    const int b = blockIdx.x >> 4, s0 = (blockIdx.x & 15) << 6;
    for (int i = t; i < 8192; i += 256) {
        int r = i >> 7, o = i & 127;
        size_t src = ((size_t)(b << 10) + s0 + r) * 128 + o;
        float a = bnsc[o];
        float m = (a >= 0.f) ? Mx[src] : Mn[src];
        T[o][r] = fmaxf(a * m + bnsh[o], 0.f);
    }
    __syncthreads();
    float* np = out + NEWP_OFF;
    for (int i = t; i < 8192; i += 256) {
        int o = i >> 6, r = i & 63;
        np[((size_t)(b << 7) + o) * 1024 + s0 + r] = T[o][r];
    }
}

extern "C" void kernel_launch(void* const* d_in, const int* in_sizes, int n_in,
                              void* d_out, int out_size, void* d_ws, size_t ws_size,
                              hipStream_t stream) {
    const float* xyz = (const float*)d_in[0];
    const float* points = (const float*)d_in[1];
    const float* w0 = (const float*)d_in[2];
    const float* b0 = (const float*)d_in[3];
    const float* g0 = (const float*)d_in[4];
    const float* bb0 = (const float*)d_in[5];
    const float* w1 = (const float*)d_in[6];
    const float* b1 = (const float*)d_in[7];
    const float* g1 = (const float*)d_in[8];
    const float* bb1 = (const float*)d_in[9];
    const float* w2 = (const float*)d_in[10];
    const float* b2 = (const float*)d_in[11];
    const float* g2 = (const float*)d_in[12];
    const float* bb2 = (const float*)d_in[13];
    float* out = (float*)d_out;
    char* ws = (char*)d_ws;

    int* knn = (int*)(ws);                               // 2 MiB
    int* fps = (int*)(ws + (2u << 20));                  // 64 KiB
    float* stats = (float*)(ws + (2u << 20) + (1u << 16));
    float *gs0 = stats, *gq0 = stats + 64, *gs1 = stats + 128, *gq1 = stats + 192;
    float *gs2 = stats + 256, *gq2 = stats + 384;
    float* Mx = (float*)(ws + (4ull << 20));             // 8 MiB
    float* Mn = (float*)(ws + (12ull << 20));            // 8 MiB
    const size_t yoff = 20ull << 20;
    const size_t ybytes_f32 = (size_t)MTOT * 64 * 4;
    const bool f32p = ws_size >= yoff + 2 * ybytes_f32;

    (void)hipMemsetAsync(stats, 0, 512 * sizeof(float), stream);
    fps_kernel<<<NB, 256, 0, stream>>>(xyz, fps);
    // ---- ATTRIBUTION PROBE: knn is idempotent (pure deterministic writes). ----
    // Launch 4x; delta vs round-10 total = 3 x knn_time.
    knn_kernel<<<NB * 32, 256, 0, stream>>>(xyz, fps, knn, out);
    knn_kernel<<<NB * 32, 256, 0, stream>>>(xyz, fps, knn, out);
    knn_kernel<<<NB * 32, 256, 0, stream>>>(xyz, fps, knn, out);
    knn_kernel<<<NB * 32, 256, 0, stream>>>(xyz, fps, knn, out);

    if (f32p) {
        float* Y0 = (float*)(ws + yoff);
        float* Y1 = Y0 + (size_t)MTOT * 64;
        conv0_kernel<float><<<4096, 256, 0, stream>>>(xyz, points, out, knn, w0, b0, Y0, gs0, gq0);
        conv1_kernel<float><<<4096, 256, 0, stream>>>(Y0, w1, b1, gs0, gq0, g0, bb0, Y1, gs1, gq1);
        conv2s_kernel<float><<<4096, 256, 0, stream>>>(Y1, w2, b2, gs1, gq1, g1, bb1, gs2, gq2, Mx, Mn);
    } else {
        __hip_bfloat16* Y0 = (__hip_bfloat16*)(ws + yoff);
        __hip_bfloat16* Y1 = Y0 + (size_t)MTOT * 64;
        conv0_kernel<__hip_bfloat16><<<4096, 256, 0, stream>>>(xyz, points, out, knn, w0, b0, Y0, gs0, gq0);
        conv1_kernel<__hip_bfloat16><<<4096, 256, 0, stream>>>(Y0, w1, b1, gs0, gq0, g0, bb0, Y1, gs1, gq1);
        conv2s_kernel<__hip_bfloat16><<<4096, 256, 0, stream>>>(Y1, w2, b2, gs1, gq1, g1, bb1, gs2, gq2, Mx, Mn);
    }
    final2_kernel<<<256, 256, 0, stream>>>(Mx, Mn, gs2, gq2, g2, bb2, out);
}

// Round 16
// 1403.029 us; speedup vs baseline: 1.5617x; 1.5617x over previous
//
#include <hip/hip_runtime.h>
#include <hip/hip_bf16.h>

#define NB 16
#define NN 4096
#define NS 1024
#define NK 32
#define CF 64
#define CIN 67
#define MTOT 524288          // NB*NS*NK
#define NEWP_OFF 49152       // NB*NS*3

__device__ inline void stY(float* p, float v) { *p = v; }
__device__ inline void stY(__hip_bfloat16* p, float v) { *p = __float2bfloat16(v); }
__device__ inline float ldY(const float* p) { return *p; }
__device__ inline float ldY(const __hip_bfloat16* p) { return __bfloat162float(*p); }
__device__ inline float4 ldY4(const float* p) { return *(const float4*)p; }
__device__ inline float4 ldY4(const __hip_bfloat16* p) {
    return make_float4(ldY(p), ldY(p + 1), ldY(p + 2), ldY(p + 3));
}
__device__ inline void stY4(float* p, float4 v) { *(float4*)p = v; }
__device__ inline void stY4(__hip_bfloat16* p, float4 v) {
    stY(p, v.x); stY(p + 1, v.y); stY(p + 2, v.z); stY(p + 3, v.w);
}

// ---- DPP reduce helpers (ctrl must be ICE -> template) -------------------------
template <int CTRL>
__device__ inline float dppredmax(float v) {
    int j = __builtin_amdgcn_update_dpp(__float_as_int(v), __float_as_int(v),
                                        CTRL, 0xF, 0xF, false);
    return fmaxf(v, __int_as_float(j));
}
template <int CTRL>
__device__ inline float dppredmin(float v) {
    int j = __builtin_amdgcn_update_dpp(__float_as_int(v), __float_as_int(v),
                                        CTRL, 0xF, 0xF, false);
    return fminf(v, __int_as_float(j));
}
template <int CTRL>
__device__ inline float dppadd0(float v) {   // bound_ctrl=1: invalid lanes read 0
    int j = __builtin_amdgcn_update_dpp(0, __float_as_int(v), CTRL, 0xF, 0xF, true);
    return __fadd_rn(v, __int_as_float(j));
}
template <int CTRL>
__device__ inline unsigned dppminu(unsigned v) {   // mov_dpp + v_min_u32
    unsigned j = (unsigned)__builtin_amdgcn_update_dpp((int)v, (int)v, CTRL, 0xF, 0xF, false);
    return j < v ? j : v;
}
__device__ inline float wavemax_to_all(float tmax) {
    float g = tmax;
    g = dppredmax<0x111>(g);   // row_shr:1
    g = dppredmax<0x112>(g);   // row_shr:2
    g = dppredmax<0x114>(g);   // row_shr:4
    g = dppredmax<0x118>(g);   // row_shr:8
    g = dppredmax<0x142>(g);   // row_bcast15
    g = dppredmax<0x143>(g);   // row_bcast31 -> lane 63 = wave max
    return __int_as_float(__builtin_amdgcn_readlane(__float_as_int(g), 63));
}
__device__ inline unsigned waveminu_to_all(unsigned v) {
    v = dppminu<0x111>(v); v = dppminu<0x112>(v); v = dppminu<0x114>(v);
    v = dppminu<0x118>(v); v = dppminu<0x142>(v); v = dppminu<0x143>(v);
    return (unsigned)__builtin_amdgcn_readlane((int)v, 63);
}
__device__ inline float segsum16(float v) {    // lanes 15,31,47,63 hold 16-seg sum
    v = dppadd0<0x111>(v); v = dppadd0<0x112>(v);
    v = dppadd0<0x114>(v); v = dppadd0<0x118>(v);
    return v;
}
__device__ inline float segsum32(float v) {    // lanes 31,63 hold 32-seg sum
    v = segsum16(v); v = dppadd0<0x142>(v);
    return v;
}
__device__ inline float quadmax(float v) {     // all 4 lanes of quad hold max
    v = dppredmax<0xB1>(v); v = dppredmax<0x4E>(v);
    return v;
}
__device__ inline float quadmin(float v) {
    v = dppredmin<0xB1>(v); v = dppredmin<0x4E>(v);
    return v;
}

// -------- FPS (round-6 proven, 594us): cpt LDS + all-DPP max + u64 part --------
__global__ __launch_bounds__(256) void fps_kernel(const float* __restrict__ xyz,
                                                  int* __restrict__ fps_idx) {
    __shared__ float4 cpt[NN];                  // 64 KiB packed coords
    __shared__ unsigned long long part[2][4];
    const int b = blockIdx.x, t = threadIdx.x;
    const float4* src = (const float4*)(xyz + (size_t)b * NN * 3);
    float px[16], py[16], pz[16], dist[16];
#pragma unroll
    for (int j = 0; j < 4; ++j) {
        float4 A = src[t * 12 + 3 * j], B4 = src[t * 12 + 3 * j + 1], C4 = src[t * 12 + 3 * j + 2];
        px[4 * j + 0] = A.x;  py[4 * j + 0] = A.y;  pz[4 * j + 0] = A.z;
        px[4 * j + 1] = A.w;  py[4 * j + 1] = B4.x; pz[4 * j + 1] = B4.y;
        px[4 * j + 2] = B4.z; py[4 * j + 2] = B4.w; pz[4 * j + 2] = C4.x;
        px[4 * j + 3] = C4.y; py[4 * j + 3] = C4.z; pz[4 * j + 3] = C4.w;
    }
#pragma unroll
    for (int i = 0; i < 16; ++i) {
        dist[i] = 1e10f;
        cpt[16 * t + i] = make_float4(px[i], py[i], pz[i], 0.f);
    }
    __syncthreads();
    int cur = 0;
    float4 c = cpt[0];
    const int wv = t >> 6;
    for (int s = 0; s < NS; ++s) {
        if (t == 0) fps_idx[(b << 10) + s] = cur;
#pragma unroll
        for (int i = 0; i < 16; ++i) {
            float dx = __fsub_rn(px[i], c.x), dy = __fsub_rn(py[i], c.y), dz = __fsub_rn(pz[i], c.z);
            float d = __fadd_rn(__fadd_rn(__fmul_rn(dx, dx), __fmul_rn(dy, dy)), __fmul_rn(dz, dz));
            dist[i] = fminf(dist[i], d);
        }
        float m0 = fmaxf(dist[0], dist[1]),   m1 = fmaxf(dist[2], dist[3]);
        float m2 = fmaxf(dist[4], dist[5]),   m3 = fmaxf(dist[6], dist[7]);
        float m4 = fmaxf(dist[8], dist[9]),   m5 = fmaxf(dist[10], dist[11]);
        float m6 = fmaxf(dist[12], dist[13]), m7 = fmaxf(dist[14], dist[15]);
        m0 = fmaxf(m0, m1); m2 = fmaxf(m2, m3); m4 = fmaxf(m4, m5); m6 = fmaxf(m6, m7);
        m0 = fmaxf(m0, m2); m4 = fmaxf(m4, m6);
        const float tmax = fmaxf(m0, m4);
        int mi = 15;
#pragma unroll
        for (int i = 14; i >= 0; --i) mi = (dist[i] == tmax) ? i : mi;
        const float gmax = wavemax_to_all(tmax);
        unsigned long long mask = __ballot(tmax == gmax);
        int ldr = __ffsll(mask) - 1;
        int widx = __builtin_amdgcn_readlane(16 * t + mi, ldr);
        if ((t & 63) == 0) {
            part[s & 1][wv] =
                ((unsigned long long)__float_as_uint(gmax) << 32) | (unsigned)(4095 - widx);
        }
        __syncthreads();
        unsigned long long k0 = part[s & 1][0], k1 = part[s & 1][1];
        unsigned long long k2 = part[s & 1][2], k3 = part[s & 1][3];
        unsigned long long ka = k0 > k1 ? k0 : k1, kb = k2 > k3 ? k2 : k3;
        unsigned long long k = ka > kb ? ka : kb;
        cur = 4095 - (int)(unsigned)(k & 0xffffffffu);
        c = cpt[cur];
    }
}

// ---- kNN v3: 512-thr blocks (16 waves/CU), 2-stage u32 DPP min extraction ------
__global__ __launch_bounds__(512) void knn_kernel(const float* __restrict__ xyz,
                                                  const int* __restrict__ fps_idx,
                                                  int* __restrict__ knn,
                                                  float* __restrict__ out) {
    __shared__ float4 cpt[NN];                  // {x,y,z,|p|^2}
    const int b = blockIdx.x >> 5, cb = blockIdx.x & 31, t = threadIdx.x;
    for (int p = t; p < NN; p += 512) {
        const float* xr = xyz + ((size_t)(b << 12) + p) * 3;
        float x = xr[0], y = xr[1], z = xr[2];
        float pn = __fadd_rn(__fadd_rn(__fmul_rn(x, x), __fmul_rn(y, y)), __fmul_rn(z, z));
        cpt[p] = make_float4(x, y, z, pn);
    }
    __syncthreads();
    const int lane = t & 63, wv = t >> 6;      // wv 0..7
    for (int r = 0; r < 4; ++r) {
        const int s = (cb << 5) + (wv << 2) + r;
        const int ci = fps_idx[(b << 10) + s];
        const float4 cq = cpt[ci];
        const float cx = cq.x, cy = cq.y, cz = cq.z, cn = cq.w;
        if (lane < 3) out[((size_t)(b << 10) + s) * 3 + lane] = (lane == 0) ? cx : (lane == 1 ? cy : cz);
        unsigned long long m1 = ~0ULL, m2 = ~0ULL, m3 = ~0ULL;
#pragma unroll
        for (int i = 0; i < 64; ++i) {
            int p = lane + (i << 6);
            float4 q = cpt[p];
            float dot = __fadd_rn(__fadd_rn(__fmul_rn(cx, q.x), __fmul_rn(cy, q.y)),
                                  __fmul_rn(cz, q.z));
            float d2 = __fsub_rn(__fadd_rn(cn, q.w), __fmul_rn(2.0f, dot));
            unsigned u = __float_as_uint(d2);
            unsigned enc = u ^ ((unsigned)((int)u >> 31) | 0x80000000u);
            unsigned long long key = ((unsigned long long)enc << 32) | (unsigned)p;
            if (key < m3) {
                if (key < m1)      { m3 = m2; m2 = m1; m1 = key; }
                else if (key < m2) { m3 = m2; m2 = key; }
                else               { m3 = key; }
            }
        }
        unsigned myidx = 0;
        for (int j = 0; j < 32; ++j) {
            // lexicographic (enc, p) min == u64 min, done as two u32 min chains
            const unsigned m1e = (unsigned)(m1 >> 32);
            const unsigned ge = waveminu_to_all(m1e);
            const unsigned cand = (m1e == ge) ? (unsigned)m1 : 0xFFFFFFFFu;
            const unsigned cp = waveminu_to_all(cand);
            if (lane == j) myidx = cp;
            const unsigned long long vmin = ((unsigned long long)ge << 32) | cp;
            if (m1 == vmin) {
                m1 = m2; m2 = m3; m3 = ~0ULL;
                if (m1 == ~0ULL) {
#pragma unroll
                    for (int i = 0; i < 64; ++i) {
                        int p = lane + (i << 6);
                        float4 q = cpt[p];
                        float dot = __fadd_rn(__fadd_rn(__fmul_rn(cx, q.x), __fmul_rn(cy, q.y)),
                                              __fmul_rn(cz, q.z));
                        float d2 = __fsub_rn(__fadd_rn(cn, q.w), __fmul_rn(2.0f, dot));
                        unsigned u = __float_as_uint(d2);
                        unsigned enc = u ^ ((unsigned)((int)u >> 31) | 0x80000000u);
                        unsigned long long key = ((unsigned long long)enc << 32) | (unsigned)p;
                        if (key > vmin && key < m3) {
                            if (key < m1)      { m3 = m2; m2 = m1; m1 = key; }
                            else if (key < m2) { m3 = m2; m2 = key; }
                            else               { m3 = key; }
                        }
                    }
                }
            }
        }
        const int rowbase = ((b << 10) + s) << 5;
        if (lane < 32) knn[rowbase + lane] = (int)myidx;
    }
}

// ------ conv0: tiled GEMM. TILE_E=128, C=67, O=64. thread: 4 elem x 8 out -------
template <typename YT>
__global__ __launch_bounds__(256) void conv0_kernel(
    const float* __restrict__ xyz, const float* __restrict__ points,
    const float* __restrict__ out_xyz, const int* __restrict__ knn,
    const float* __restrict__ w0, const float* __restrict__ b0,
    YT* __restrict__ Y0, float* __restrict__ gs, float* __restrict__ gq) {
    __shared__ float Ht[CIN][128];
    __shared__ float Wt[CIN][64];
    __shared__ float bsm[64], bqm[64];
    const int t = threadIdx.x;
    const int eb = blockIdx.x << 7;
    for (int i = t; i < CIN * 64; i += 256) {
        int c = i >> 6, o = i & 63;
        Wt[c][o] = w0[o * CIN + c];
    }
    {
        const int le = t >> 1, part = t & 1;
        const int e = eb + le;
        const int b = e >> 15, s = (e >> 5) & 1023;
        const int pidx = knn[e];
        const float4* pr = (const float4*)(points + (((size_t)(b << 12) + pidx) << 6)) + (part << 3);
        if (part == 0) {
            const float* xr = xyz + ((size_t)(b << 12) + pidx) * 3;
            const float* cr = out_xyz + ((size_t)(b << 10) + s) * 3;
            Ht[0][le] = xr[0] - cr[0];
            Ht[1][le] = xr[1] - cr[1];
            Ht[2][le] = xr[2] - cr[2];
        }
#pragma unroll
        for (int q = 0; q < 8; ++q) {
            float4 v = pr[q];
            int c = 3 + (part << 5) + (q << 2);
            Ht[c][le] = v.x; Ht[c + 1][le] = v.y; Ht[c + 2][le] = v.z; Ht[c + 3][le] = v.w;
        }
    }
    __syncthreads();
    const int te = t & 31, to = t >> 5;
    float acc[4][8];
#pragma unroll
    for (int j = 0; j < 4; ++j)
#pragma unroll
        for (int i = 0; i < 8; ++i) acc[j][i] = 0.f;
#pragma unroll 2
    for (int c = 0; c < CIN; ++c) {
        const float4 a0 = *(const float4*)&Ht[c][te << 2];
        const float4 wa = *(const float4*)&Wt[c][to << 3];
        const float4 wb = *(const float4*)&Wt[c][(to << 3) + 4];
        const float av[4] = {a0.x, a0.y, a0.z, a0.w};
        const float wvv[8] = {wa.x, wa.y, wa.z, wa.w, wb.x, wb.y, wb.z, wb.w};
#pragma unroll
        for (int j = 0; j < 4; ++j)
#pragma unroll
            for (int i = 0; i < 8; ++i) acc[j][i] += av[j] * wvv[i];
    }
    const int o0 = to << 3;
    float s1v[8], s2v[8];
#pragma unroll
    for (int i = 0; i < 8; ++i) {
        const float bi = b0[o0 + i];
        float ss = 0.f, qq = 0.f;
#pragma unroll
        for (int j = 0; j < 4; ++j) {
            float v = acc[j][i] + bi;
            acc[j][i] = v;
            ss += v; qq += v * v;
        }
        s1v[i] = ss; s2v[i] = qq;
    }
#pragma unroll
    for (int i = 0; i < 8; ++i) {
        const size_t base = (size_t)(o0 + i) * MTOT + eb + (te << 2);
        stY4(&Y0[base], make_float4(acc[0][i], acc[1][i], acc[2][i], acc[3][i]));
    }
#pragma unroll
    for (int i = 0; i < 8; ++i) { s1v[i] = segsum32(s1v[i]); s2v[i] = segsum32(s2v[i]); }
    if ((t & 31) == 31) {
#pragma unroll
        for (int i = 0; i < 8; ++i) { bsm[o0 + i] = s1v[i]; bqm[o0 + i] = s2v[i]; }
    }
    __syncthreads();
    if (t < 64) atomicAdd(&gs[t], bsm[t]);
    else if (t < 128) atomicAdd(&gq[t - 64], bqm[t - 64]);
}

// ------ conv1: tiled GEMM + in-block BN0 finalize. thread: 8 elem x 4 out -------
template <typename YT>
__global__ __launch_bounds__(256) void conv1_kernel(
    const YT* __restrict__ Y0, const float* __restrict__ w1, const float* __restrict__ b1,
    const float* __restrict__ gsp, const float* __restrict__ gqp,
    const float* __restrict__ g, const float* __restrict__ bb,
    YT* __restrict__ Y1, float* __restrict__ gs, float* __restrict__ gq) {
    __shared__ float At[64][128];
    __shared__ float Wt[64][64];
    __shared__ float bnsc[64], bnsh[64];
    __shared__ float bsm[64], bqm[64];
    const int t = threadIdx.x;
    const int eb = blockIdx.x << 7;
    if (t < 64) {
        const float inv = 1.f / (float)MTOT;
        float mean = gsp[t] * inv;
        float var = gqp[t] * inv - mean * mean;
        float r = g[t] / sqrtf(var + 1e-5f);
        bnsc[t] = r; bnsh[t] = bb[t] - mean * r;
    }
    for (int i = t; i < 4096; i += 256) {
        int c = i >> 6, o = i & 63;
        Wt[c][o] = w1[o * 64 + c];
    }
    __syncthreads();
#pragma unroll
    for (int r = 0; r < 8; ++r) {
        int L = (r << 8) + t;                 // float4 id
        int c = L >> 5, col = (L & 31) << 2;
        float4 y = ldY4(&Y0[(size_t)c * MTOT + eb + col]);
        float sx = bnsc[c], hx = bnsh[c];
        At[c][col]     = fmaxf(sx * y.x + hx, 0.f);
        At[c][col + 1] = fmaxf(sx * y.y + hx, 0.f);
        At[c][col + 2] = fmaxf(sx * y.z + hx, 0.f);
        At[c][col + 3] = fmaxf(sx * y.w + hx, 0.f);
    }
    __syncthreads();
    const int te = t & 15, to = t >> 4;
    float acc[8][4];
#pragma unroll
    for (int j = 0; j < 8; ++j)
#pragma unroll
        for (int i = 0; i < 4; ++i) acc[j][i] = 0.f;
#pragma unroll 2
    for (int c = 0; c < 64; ++c) {
        const float4 a0 = *(const float4*)&At[c][te << 3];
        const float4 a1 = *(const float4*)&At[c][(te << 3) + 4];
        const float4 wa = *(const float4*)&Wt[c][to << 2];
        const float av[8] = {a0.x, a0.y, a0.z, a0.w, a1.x, a1.y, a1.z, a1.w};
        const float wvv[4] = {wa.x, wa.y, wa.z, wa.w};
#pragma unroll
        for (int j = 0; j < 8; ++j)
#pragma unroll
            for (int i = 0; i < 4; ++i) acc[j][i] += av[j] * wvv[i];
    }
    const int o0 = to << 2;
    float s1v[4], s2v[4];
#pragma unroll
    for (int i = 0; i < 4; ++i) {
        const float bi = b1[o0 + i];
        float ss = 0.f, qq = 0.f;
#pragma unroll
        for (int j = 0; j < 8; ++j) {
            float v = acc[j][i] + bi;
            acc[j][i] = v;
            ss += v; qq += v * v;
        }
        s1v[i] = ss; s2v[i] = qq;
    }
#pragma unroll
    for (int i = 0; i < 4; ++i) {
        const size_t base = (size_t)(o0 + i) * MTOT + eb + (te << 3);
        stY4(&Y1[base],     make_float4(acc[0][i], acc[1][i], acc[2][i], acc[3][i]));
        stY4(&Y1[base + 4], make_float4(acc[4][i], acc[5][i], acc[6][i], acc[7][i]));
    }
#pragma unroll
    for (int i = 0; i < 4; ++i) { s1v[i] = segsum16(s1v[i]); s2v[i] = segsum16(s2v[i]); }
    if ((t & 15) == 15) {
#pragma unroll
        for (int i = 0; i < 4; ++i) { bsm[o0 + i] = s1v[i]; bqm[o0 + i] = s2v[i]; }
    }
    __syncthreads();
    if (t < 64) atomicAdd(&gs[t], bsm[t]);
    else if (t < 128) atomicAdd(&gq[t - 64], bqm[t - 64]);
}

// ------ conv2s: tiled GEMM + in-block BN1 finalize. thread: 8 elem x 8 out ------
template <typename YT>
__global__ __launch_bounds__(256) void conv2s_kernel(
    const YT* __restrict__ Y1, const float* __restrict__ w2, const float* __restrict__ b2,
    const float* __restrict__ gsp, const float* __restrict__ gqp,
    const float* __restrict__ g, const float* __restrict__ bb,
    float* __restrict__ gs, float* __restrict__ gq,
    float* __restrict__ Mx, float* __restrict__ Mn) {
    __shared__ float At[64][128];
    __shared__ float Wt[64][128];
    __shared__ float bnsc[64], bnsh[64];
    __shared__ float bsm[128], bqm[128];
    __shared__ float mxs[4][128], mns[4][128];
    const int t = threadIdx.x;
    const int eb = blockIdx.x << 7;
    if (t < 64) {
        const float inv = 1.f / (float)MTOT;
        float mean = gsp[t] * inv;
        float var = gqp[t] * inv - mean * mean;
        float r = g[t] / sqrtf(var + 1e-5f);
        bnsc[t] = r; bnsh[t] = bb[t] - mean * r;
    }
    for (int i = t; i < 8192; i += 256) {
        int o = i & 127, c = i >> 7;
        Wt[c][o] = w2[o * 64 + c];
    }
    __syncthreads();
#pragma unroll
    for (int r = 0; r < 8; ++r) {
        int L = (r << 8) + t;
        int c = L >> 5, col = (L & 31) << 2;
        float4 y = ldY4(&Y1[(size_t)c * MTOT + eb + col]);
        float sx = bnsc[c], hx = bnsh[c];
        At[c][col]     = fmaxf(sx * y.x + hx, 0.f);
        At[c][col + 1] = fmaxf(sx * y.y + hx, 0.f);
        At[c][col + 2] = fmaxf(sx * y.z + hx, 0.f);
        At[c][col + 3] = fmaxf(sx * y.w + hx, 0.f);
    }
    __syncthreads();
    const int te = t & 15, to = t >> 4;
    float acc[8][8];
#pragma unroll
    for (int j = 0; j < 8; ++j)
#pragma unroll
        for (int i = 0; i < 8; ++i) acc[j][i] = 0.f;
#pragma unroll 2
    for (int c = 0; c < 64; ++c) {
        const float4 a0 = *(const float4*)&At[c][te << 3];
        const float4 a1 = *(const float4*)&At[c][(te << 3) + 4];
        const float4 wa = *(const float4*)&Wt[c][to << 3];
        const float4 wb = *(const float4*)&Wt[c][(to << 3) + 4];
        const float av[8] = {a0.x, a0.y, a0.z, a0.w, a1.x, a1.y, a1.z, a1.w};
        const float wvv[8] = {wa.x, wa.y, wa.z, wa.w, wb.x, wb.y, wb.z, wb.w};
#pragma unroll
        for (int j = 0; j < 8; ++j)
#pragma unroll
            for (int i = 0; i < 8; ++i) acc[j][i] += av[j] * wvv[i];
    }
    const int o0 = to << 3;
    float s1v[8], s2v[8], mxv[8], mnv[8];
#pragma unroll
    for (int i = 0; i < 8; ++i) {
        const float bi = b2[o0 + i];
        float ss = 0.f, qq = 0.f;
        float mx = -3.4e38f, mn = 3.4e38f;
#pragma unroll
        for (int j = 0; j < 8; ++j) {
            float v = acc[j][i] + bi;
            ss += v; qq += v * v;
            mx = fmaxf(mx, v); mn = fminf(mn, v);
        }
        s1v[i] = ss; s2v[i] = qq; mxv[i] = mx; mnv[i] = mn;
    }
#pragma unroll
    for (int i = 0; i < 8; ++i) {
        s1v[i] = segsum16(s1v[i]); s2v[i] = segsum16(s2v[i]);
        mxv[i] = quadmax(mxv[i]);  mnv[i] = quadmin(mnv[i]);
    }
    if ((t & 15) == 15) {
#pragma unroll
        for (int i = 0; i < 8; ++i) { bsm[o0 + i] = s1v[i]; bqm[o0 + i] = s2v[i]; }
    }
    if ((t & 3) == 0) {
        const int srow = (t & 15) >> 2;
#pragma unroll
        for (int i = 0; i < 8; ++i) { mxs[srow][o0 + i] = mxv[i]; mns[srow][o0 + i] = mnv[i]; }
    }
    __syncthreads();
    if (t < 128) atomicAdd(&gs[t], bsm[t]);
    else atomicAdd(&gq[t - 128], bqm[t - 128]);
    const int sidx0 = blockIdx.x << 2;
    for (int i = t; i < 512; i += 256) {
        int row = i >> 7, o = i & 127;
        Mx[(size_t)(sidx0 + row) * 128 + o] = mxs[row][o];
        Mn[(size_t)(sidx0 + row) * 128 + o] = mns[row][o];
    }
}

// ------- final2: in-block BN2 finalize + relu on extreme over k + transpose -----
__global__ __launch_bounds__(256) void final2_kernel(
    const float* __restrict__ Mx, const float* __restrict__ Mn,
    const float* __restrict__ gsp, const float* __restrict__ gqp,
    const float* __restrict__ g, const float* __restrict__ bb,
    float* __restrict__ out) {
    __shared__ float T[128][65];
    __shared__ float bnsc[128], bnsh[128];
    const int t = threadIdx.x;
    if (t < 128) {
        const float inv = 1.f / (float)MTOT;
        float mean = gsp[t] * inv;
        float var = gqp[t] * inv - mean * mean;
        float r = g[t] / sqrtf(var + 1e-5f);
        bnsc[t] = r; bnsh[t] = bb[t] - mean * r;
    }
    __syncthreads();
    const int b = blockIdx.x >> 4, s0 = (blockIdx.x & 15) << 6;
    for (int i = t; i < 8192; i += 256) {
        int r = i >> 7, o = i & 127;
        size_t src = ((size_t)(b << 10) + s0 + r) * 128 + o;
        float a = bnsc[o];
        float m = (a >= 0.f) ? Mx[src] : Mn[src];
        T[o][r] = fmaxf(a * m + bnsh[o], 0.f);
    }
    __syncthreads();
    float* np = out + NEWP_OFF;
    for (int i = t; i < 8192; i += 256) {
        int o = i >> 6, r = i & 63;
        np[((size_t)(b << 7) + o) * 1024 + s0 + r] = T[o][r];
    }
}

extern "C" void kernel_launch(void* const* d_in, const int* in_sizes, int n_in,
                              void* d_out, int out_size, void* d_ws, size_t ws_size,
                              hipStream_t stream) {
    const float* xyz = (const float*)d_in[0];
    const float* points = (const float*)d_in[1];
    const float* w0 = (const float*)d_in[2];
    const float* b0 = (const float*)d_in[3];
    const float* g0 = (const float*)d_in[4];
    const float* bb0 = (const float*)d_in[5];
    const float* w1 = (const float*)d_in[6];
    const float* b1 = (const float*)d_in[7];
    const float* g1 = (const float*)d_in[8];
    const float* bb1 = (const float*)d_in[9];
    const float* w2 = (const float*)d_in[10];
    const float* b2 = (const float*)d_in[11];
    const float* g2 = (const float*)d_in[12];
    const float* bb2 = (const float*)d_in[13];
    float* out = (float*)d_out;
    char* ws = (char*)d_ws;

    int* knn = (int*)(ws);                               // 2 MiB
    int* fps = (int*)(ws + (2u << 20));                  // 64 KiB
    float* stats = (float*)(ws + (2u << 20) + (1u << 16));
    float *gs0 = stats, *gq0 = stats + 64, *gs1 = stats + 128, *gq1 = stats + 192;
    float *gs2 = stats + 256, *gq2 = stats + 384;
    float* Mx = (float*)(ws + (4ull << 20));             // 8 MiB
    float* Mn = (float*)(ws + (12ull << 20));            // 8 MiB
    const size_t yoff = 20ull << 20;
    const size_t ybytes_f32 = (size_t)MTOT * 64 * 4;
    const bool f32p = ws_size >= yoff + 2 * ybytes_f32;

    (void)hipMemsetAsync(stats, 0, 512 * sizeof(float), stream);
    fps_kernel<<<NB, 256, 0, stream>>>(xyz, fps);
    knn_kernel<<<NB * 32, 512, 0, stream>>>(xyz, fps, knn, out);

    if (f32p) {
        float* Y0 = (float*)(ws + yoff);
        float* Y1 = Y0 + (size_t)MTOT * 64;
        conv0_kernel<float><<<4096, 256, 0, stream>>>(xyz, points, out, knn, w0, b0, Y0, gs0, gq0);
        conv1_kernel<float><<<4096, 256, 0, stream>>>(Y0, w1, b1, gs0, gq0, g0, bb0, Y1, gs1, gq1);
        conv2s_kernel<float><<<4096, 256, 0, stream>>>(Y1, w2, b2, gs1, gq1, g1, bb1, gs2, gq2, Mx, Mn);
    } else {
        __hip_bfloat16* Y0 = (__hip_bfloat16*)(ws + yoff);
        __hip_bfloat16* Y1 = Y0 + (size_t)MTOT * 64;
        conv0_kernel<__hip_bfloat16><<<4096, 256, 0, stream>>>(xyz, points, out, knn, w0, b0, Y0, gs0, gq0);
        conv1_kernel<__hip_bfloat16><<<4096, 256, 0, stream>>>(Y0, w1, b1, gs0, gq0, g0, bb0, Y1, gs1, gq1);
        conv2s_kernel<__hip_bfloat16><<<4096, 256, 0, stream>>>(Y1, w2, b2, gs1, gq1, g1, bb1, gs2, gq2, Mx, Mn);
    }
    final2_kernel<<<256, 256, 0, stream>>>(Mx, Mn, gs2, gq2, g2, bb2, out);
}

// Round 17
// 1295.494 us; speedup vs baseline: 1.6914x; 1.0830x over previous
//
#include <hip/hip_runtime.h>
#include <hip/hip_bf16.h>

#define NB 16
#define NN 4096
#define NS 1024
#define NK 32
#define CF 64
#define CIN 67
#define MTOT 524288          // NB*NS*NK
#define NEWP_OFF 49152       // NB*NS*3

__device__ inline void stY(float* p, float v) { *p = v; }
__device__ inline void stY(__hip_bfloat16* p, float v) { *p = __float2bfloat16(v); }
__device__ inline float ldY(const float* p) { return *p; }
__device__ inline float ldY(const __hip_bfloat16* p) { return __bfloat162float(*p); }
__device__ inline float4 ldY4(const float* p) { return *(const float4*)p; }
__device__ inline float4 ldY4(const __hip_bfloat16* p) {
    return make_float4(ldY(p), ldY(p + 1), ldY(p + 2), ldY(p + 3));
}
__device__ inline void stY4(float* p, float4 v) { *(float4*)p = v; }
__device__ inline void stY4(__hip_bfloat16* p, float4 v) {
    stY(p, v.x); stY(p + 1, v.y); stY(p + 2, v.z); stY(p + 3, v.w);
}

// ---- DPP reduce helpers (ctrl must be ICE -> template) -------------------------
template <int CTRL>
__device__ inline float dppredmax(float v) {
    int j = __builtin_amdgcn_update_dpp(__float_as_int(v), __float_as_int(v),
                                        CTRL, 0xF, 0xF, false);
    return fmaxf(v, __int_as_float(j));
}
template <int CTRL>
__device__ inline float dppredmin(float v) {
    int j = __builtin_amdgcn_update_dpp(__float_as_int(v), __float_as_int(v),
                                        CTRL, 0xF, 0xF, false);
    return fminf(v, __int_as_float(j));
}
template <int CTRL>
__device__ inline float dppadd0(float v) {   // bound_ctrl=1: invalid lanes read 0
    int j = __builtin_amdgcn_update_dpp(0, __float_as_int(v), CTRL, 0xF, 0xF, true);
    return __fadd_rn(v, __int_as_float(j));
}
template <int CTRL>
__device__ inline unsigned dppminu(unsigned v) {   // mov_dpp + v_min_u32
    unsigned j = (unsigned)__builtin_amdgcn_update_dpp((int)v, (int)v, CTRL, 0xF, 0xF, false);
    return j < v ? j : v;
}
__device__ inline float wavemax_to_all(float tmax) {
    float g = tmax;
    g = dppredmax<0x111>(g);   // row_shr:1
    g = dppredmax<0x112>(g);   // row_shr:2
    g = dppredmax<0x114>(g);   // row_shr:4
    g = dppredmax<0x118>(g);   // row_shr:8
    g = dppredmax<0x142>(g);   // row_bcast15
    g = dppredmax<0x143>(g);   // row_bcast31 -> lane 63 = wave max
    return __int_as_float(__builtin_amdgcn_readlane(__float_as_int(g), 63));
}
__device__ inline unsigned waveminu_to_all(unsigned v) {
    v = dppminu<0x111>(v); v = dppminu<0x112>(v); v = dppminu<0x114>(v);
    v = dppminu<0x118>(v); v = dppminu<0x142>(v); v = dppminu<0x143>(v);
    return (unsigned)__builtin_amdgcn_readlane((int)v, 63);
}
__device__ inline float segsum16(float v) {    // lanes 15,31,47,63 hold 16-seg sum
    v = dppadd0<0x111>(v); v = dppadd0<0x112>(v);
    v = dppadd0<0x114>(v); v = dppadd0<0x118>(v);
    return v;
}
__device__ inline float segsum32(float v) {    // lanes 31,63 hold 32-seg sum
    v = segsum16(v); v = dppadd0<0x142>(v);
    return v;
}
__device__ inline float quadmax(float v) {     // all 4 lanes of quad hold max
    v = dppredmax<0xB1>(v); v = dppredmax<0x4E>(v);
    return v;
}
__device__ inline float quadmin(float v) {
    v = dppredmin<0xB1>(v); v = dppredmin<0x4E>(v);
    return v;
}

// -------- FPS (round-6 proven, 594us): cpt LDS + all-DPP max + u64 part --------
__global__ __launch_bounds__(256) void fps_kernel(const float* __restrict__ xyz,
                                                  int* __restrict__ fps_idx) {
    __shared__ float4 cpt[NN];                  // 64 KiB packed coords
    __shared__ unsigned long long part[2][4];
    const int b = blockIdx.x, t = threadIdx.x;
    const float4* src = (const float4*)(xyz + (size_t)b * NN * 3);
    float px[16], py[16], pz[16], dist[16];
#pragma unroll
    for (int j = 0; j < 4; ++j) {
        float4 A = src[t * 12 + 3 * j], B4 = src[t * 12 + 3 * j + 1], C4 = src[t * 12 + 3 * j + 2];
        px[4 * j + 0] = A.x;  py[4 * j + 0] = A.y;  pz[4 * j + 0] = A.z;
        px[4 * j + 1] = A.w;  py[4 * j + 1] = B4.x; pz[4 * j + 1] = B4.y;
        px[4 * j + 2] = B4.z; py[4 * j + 2] = B4.w; pz[4 * j + 2] = C4.x;
        px[4 * j + 3] = C4.y; py[4 * j + 3] = C4.z; pz[4 * j + 3] = C4.w;
    }
#pragma unroll
    for (int i = 0; i < 16; ++i) {
        dist[i] = 1e10f;
        cpt[16 * t + i] = make_float4(px[i], py[i], pz[i], 0.f);
    }
    __syncthreads();
    int cur = 0;
    float4 c = cpt[0];
    const int wv = t >> 6;
    for (int s = 0; s < NS; ++s) {
        if (t == 0) fps_idx[(b << 10) + s] = cur;
#pragma unroll
        for (int i = 0; i < 16; ++i) {
            float dx = __fsub_rn(px[i], c.x), dy = __fsub_rn(py[i], c.y), dz = __fsub_rn(pz[i], c.z);
            float d = __fadd_rn(__fadd_rn(__fmul_rn(dx, dx), __fmul_rn(dy, dy)), __fmul_rn(dz, dz));
            dist[i] = fminf(dist[i], d);
        }
        float m0 = fmaxf(dist[0], dist[1]),   m1 = fmaxf(dist[2], dist[3]);
        float m2 = fmaxf(dist[4], dist[5]),   m3 = fmaxf(dist[6], dist[7]);
        float m4 = fmaxf(dist[8], dist[9]),   m5 = fmaxf(dist[10], dist[11]);
        float m6 = fmaxf(dist[12], dist[13]), m7 = fmaxf(dist[14], dist[15]);
        m0 = fmaxf(m0, m1); m2 = fmaxf(m2, m3); m4 = fmaxf(m4, m5); m6 = fmaxf(m6, m7);
        m0 = fmaxf(m0, m2); m4 = fmaxf(m4, m6);
        const float tmax = fmaxf(m0, m4);
        int mi = 15;
#pragma unroll
        for (int i = 14; i >= 0; --i) mi = (dist[i] == tmax) ? i : mi;
        const float gmax = wavemax_to_all(tmax);
        unsigned long long mask = __ballot(tmax == gmax);
        int ldr = __ffsll(mask) - 1;
        int widx = __builtin_amdgcn_readlane(16 * t + mi, ldr);
        if ((t & 63) == 0) {
            part[s & 1][wv] =
                ((unsigned long long)__float_as_uint(gmax) << 32) | (unsigned)(4095 - widx);
        }
        __syncthreads();
        unsigned long long k0 = part[s & 1][0], k1 = part[s & 1][1];
        unsigned long long k2 = part[s & 1][2], k3 = part[s & 1][3];
        unsigned long long ka = k0 > k1 ? k0 : k1, kb = k2 > k3 ? k2 : k3;
        unsigned long long k = ka > kb ? ka : kb;
        cur = 4095 - (int)(unsigned)(k & 0xffffffffu);
        c = cpt[cur];
    }
}

// ---- pack: {x,y,z,|p|^2} into global float4 (same rn formula as before) --------
__global__ __launch_bounds__(256) void pack_kernel(const float* __restrict__ xyz,
                                                   float4* __restrict__ cp) {
    const int i = blockIdx.x * 256 + threadIdx.x;   // 0 .. NB*NN-1
    const float* xr = xyz + (size_t)i * 3;
    float x = xr[0], y = xr[1], z = xr[2];
    float pn = __fadd_rn(__fadd_rn(__fmul_rn(x, x), __fmul_rn(y, y)), __fmul_rn(z, z));
    cp[i] = make_float4(x, y, z, pn);
}

// ---- kNN v4: no LDS (global L2 reads), u32 DPP min + ballot short-circuit ------
__global__ __launch_bounds__(256, 4) void knn_kernel(const float4* __restrict__ cpt4,
                                                     const int* __restrict__ fps_idx,
                                                     int* __restrict__ knn,
                                                     float* __restrict__ out) {
    const int b = blockIdx.x >> 5, cb = blockIdx.x & 31, t = threadIdx.x;
    const float4* __restrict__ cpt = cpt4 + ((size_t)b << 12);
    const int lane = t & 63, wv = t >> 6;
    for (int r = 0; r < 8; ++r) {
        const int s = (cb << 5) + (wv << 3) + r;
        const int ci = fps_idx[(b << 10) + s];
        const float4 cq = cpt[ci];
        const float cx = cq.x, cy = cq.y, cz = cq.z, cn = cq.w;
        if (lane < 3) out[((size_t)(b << 10) + s) * 3 + lane] = (lane == 0) ? cx : (lane == 1 ? cy : cz);
        unsigned long long m1 = ~0ULL, m2 = ~0ULL, m3 = ~0ULL;
#pragma unroll 8
        for (int i = 0; i < 64; ++i) {
            int p = lane + (i << 6);
            float4 q = cpt[p];
            float dot = __fadd_rn(__fadd_rn(__fmul_rn(cx, q.x), __fmul_rn(cy, q.y)),
                                  __fmul_rn(cz, q.z));
            float d2 = __fsub_rn(__fadd_rn(cn, q.w), __fmul_rn(2.0f, dot));
            unsigned u = __float_as_uint(d2);
            unsigned enc = u ^ ((unsigned)((int)u >> 31) | 0x80000000u);
            unsigned long long key = ((unsigned long long)enc << 32) | (unsigned)p;
            if (key < m3) {
                if (key < m1)      { m3 = m2; m2 = m1; m1 = key; }
                else if (key < m2) { m3 = m2; m2 = key; }
                else               { m3 = key; }
            }
        }
        unsigned myidx = 0;
        for (int j = 0; j < 32; ++j) {
            // min over (enc, p): u32 chain on enc; ballot picks owner; tie path rare
            const unsigned m1e = (unsigned)(m1 >> 32);
            const unsigned ge = waveminu_to_all(m1e);
            const unsigned long long mask = __ballot(m1e == ge);
            unsigned cp;
            if (__popcll(mask) == 1) {
                cp = (unsigned)__builtin_amdgcn_readlane((int)(unsigned)m1,
                                                         __ffsll(mask) - 1);
            } else {
                unsigned cand = (m1e == ge) ? (unsigned)m1 : 0xFFFFFFFFu;
                cp = waveminu_to_all(cand);
            }
            if (lane == j) myidx = cp;
            const unsigned long long vmin = ((unsigned long long)ge << 32) | cp;
            if (m1 == vmin) {
                m1 = m2; m2 = m3; m3 = ~0ULL;
                if (m1 == ~0ULL) {
#pragma unroll 8
                    for (int i = 0; i < 64; ++i) {
                        int p = lane + (i << 6);
                        float4 q = cpt[p];
                        float dot = __fadd_rn(__fadd_rn(__fmul_rn(cx, q.x), __fmul_rn(cy, q.y)),
                                              __fmul_rn(cz, q.z));
                        float d2 = __fsub_rn(__fadd_rn(cn, q.w), __fmul_rn(2.0f, dot));
                        unsigned u = __float_as_uint(d2);
                        unsigned enc = u ^ ((unsigned)((int)u >> 31) | 0x80000000u);
                        unsigned long long key = ((unsigned long long)enc << 32) | (unsigned)p;
                        if (key > vmin && key < m3) {
                            if (key < m1)      { m3 = m2; m2 = m1; m1 = key; }
                            else if (key < m2) { m3 = m2; m2 = key; }
                            else               { m3 = key; }
                        }
                    }
                }
            }
        }
        const int rowbase = ((b << 10) + s) << 5;
        if (lane < 32) knn[rowbase + lane] = (int)myidx;
    }
}

// ------ conv0: tiled GEMM. TILE_E=128, C=67, O=64. thread: 4 elem x 8 out -------
template <typename YT>
__global__ __launch_bounds__(256) void conv0_kernel(
    const float* __restrict__ xyz, const float* __restrict__ points,
    const float* __restrict__ out_xyz, const int* __restrict__ knn,
    const float* __restrict__ w0, const float* __restrict__ b0,
    YT* __restrict__ Y0, float* __restrict__ gs, float* __restrict__ gq) {
    __shared__ float Ht[CIN][128];
    __shared__ float Wt[CIN][64];
    __shared__ float bsm[64], bqm[64];
    const int t = threadIdx.x;
    const int eb = blockIdx.x << 7;
    for (int i = t; i < CIN * 64; i += 256) {
        int c = i >> 6, o = i & 63;
        Wt[c][o] = w0[o * CIN + c];
    }
    {
        const int le = t >> 1, part = t & 1;
        const int e = eb + le;
        const int b = e >> 15, s = (e >> 5) & 1023;
        const int pidx = knn[e];
        const float4* pr = (const float4*)(points + (((size_t)(b << 12) + pidx) << 6)) + (part << 3);
        if (part == 0) {
            const float* xr = xyz + ((size_t)(b << 12) + pidx) * 3;
            const float* cr = out_xyz + ((size_t)(b << 10) + s) * 3;
            Ht[0][le] = xr[0] - cr[0];
            Ht[1][le] = xr[1] - cr[1];
            Ht[2][le] = xr[2] - cr[2];
        }
#pragma unroll
        for (int q = 0; q < 8; ++q) {
            float4 v = pr[q];
            int c = 3 + (part << 5) + (q << 2);
            Ht[c][le] = v.x; Ht[c + 1][le] = v.y; Ht[c + 2][le] = v.z; Ht[c + 3][le] = v.w;
        }
    }
    __syncthreads();
    const int te = t & 31, to = t >> 5;
    float acc[4][8];
#pragma unroll
    for (int j = 0; j < 4; ++j)
#pragma unroll
        for (int i = 0; i < 8; ++i) acc[j][i] = 0.f;
#pragma unroll 2
    for (int c = 0; c < CIN; ++c) {
        const float4 a0 = *(const float4*)&Ht[c][te << 2];
        const float4 wa = *(const float4*)&Wt[c][to << 3];
        const float4 wb = *(const float4*)&Wt[c][(to << 3) + 4];
        const float av[4] = {a0.x, a0.y, a0.z, a0.w};
        const float wvv[8] = {wa.x, wa.y, wa.z, wa.w, wb.x, wb.y, wb.z, wb.w};
#pragma unroll
        for (int j = 0; j < 4; ++j)
#pragma unroll
            for (int i = 0; i < 8; ++i) acc[j][i] += av[j] * wvv[i];
    }
    const int o0 = to << 3;
    float s1v[8], s2v[8];
#pragma unroll
    for (int i = 0; i < 8; ++i) {
        const float bi = b0[o0 + i];
        float ss = 0.f, qq = 0.f;
#pragma unroll
        for (int j = 0; j < 4; ++j) {
            float v = acc[j][i] + bi;
            acc[j][i] = v;
            ss += v; qq += v * v;
        }
        s1v[i] = ss; s2v[i] = qq;
    }
#pragma unroll
    for (int i = 0; i < 8; ++i) {
        const size_t base = (size_t)(o0 + i) * MTOT + eb + (te << 2);
        stY4(&Y0[base], make_float4(acc[0][i], acc[1][i], acc[2][i], acc[3][i]));
    }
#pragma unroll
    for (int i = 0; i < 8; ++i) { s1v[i] = segsum32(s1v[i]); s2v[i] = segsum32(s2v[i]); }
    if ((t & 31) == 31) {
#pragma unroll
        for (int i = 0; i < 8; ++i) { bsm[o0 + i] = s1v[i]; bqm[o0 + i] = s2v[i]; }
    }
    __syncthreads();
    if (t < 64) atomicAdd(&gs[t], bsm[t]);
    else if (t < 128) atomicAdd(&gq[t - 64], bqm[t - 64]);
}

// ------ conv1: tiled GEMM + in-block BN0 finalize. thread: 8 elem x 4 out -------
template <typename YT>
__global__ __launch_bounds__(256) void conv1_kernel(
    const YT* __restrict__ Y0, const float* __restrict__ w1, const float* __restrict__ b1,
    const float* __restrict__ gsp, const float* __restrict__ gqp,
    const float* __restrict__ g, const float* __restrict__ bb,
    YT* __restrict__ Y1, float* __restrict__ gs, float* __restrict__ gq) {
    __shared__ float At[64][128];
    __shared__ float Wt[64][64];
    __shared__ float bnsc[64], bnsh[64];
    __shared__ float bsm[64], bqm[64];
    const int t = threadIdx.x;
    const int eb = blockIdx.x << 7;
    if (t < 64) {
        const float inv = 1.f / (float)MTOT;
        float mean = gsp[t] * inv;
        float var = gqp[t] * inv - mean * mean;
        float r = g[t] / sqrtf(var + 1e-5f);
        bnsc[t] = r; bnsh[t] = bb[t] - mean * r;
    }
    for (int i = t; i < 4096; i += 256) {
        int c = i >> 6, o = i & 63;
        Wt[c][o] = w1[o * 64 + c];
    }
    __syncthreads();
#pragma unroll
    for (int r = 0; r < 8; ++r) {
        int L = (r << 8) + t;                 // float4 id
        int c = L >> 5, col = (L & 31) << 2;
        float4 y = ldY4(&Y0[(size_t)c * MTOT + eb + col]);
        float sx = bnsc[c], hx = bnsh[c];
        At[c][col]     = fmaxf(sx * y.x + hx, 0.f);
        At[c][col + 1] = fmaxf(sx * y.y + hx, 0.f);
        At[c][col + 2] = fmaxf(sx * y.z + hx, 0.f);
        At[c][col + 3] = fmaxf(sx * y.w + hx, 0.f);
    }
    __syncthreads();
    const int te = t & 15, to = t >> 4;
    float acc[8][4];
#pragma unroll
    for (int j = 0; j < 8; ++j)
#pragma unroll
        for (int i = 0; i < 4; ++i) acc[j][i] = 0.f;
#pragma unroll 2
    for (int c = 0; c < 64; ++c) {
        const float4 a0 = *(const float4*)&At[c][te << 3];
        const float4 a1 = *(const float4*)&At[c][(te << 3) + 4];
        const float4 wa = *(const float4*)&Wt[c][to << 2];
        const float av[8] = {a0.x, a0.y, a0.z, a0.w, a1.x, a1.y, a1.z, a1.w};
        const float wvv[4] = {wa.x, wa.y, wa.z, wa.w};
#pragma unroll
        for (int j = 0; j < 8; ++j)
#pragma unroll
            for (int i = 0; i < 4; ++i) acc[j][i] += av[j] * wvv[i];
    }
    const int o0 = to << 2;
    float s1v[4], s2v[4];
#pragma unroll
    for (int i = 0; i < 4; ++i) {
        const float bi = b1[o0 + i];
        float ss = 0.f, qq = 0.f;
#pragma unroll
        for (int j = 0; j < 8; ++j) {
            float v = acc[j][i] + bi;
            acc[j][i] = v;
            ss += v; qq += v * v;
        }
        s1v[i] = ss; s2v[i] = qq;
    }
#pragma unroll
    for (int i = 0; i < 4; ++i) {
        const size_t base = (size_t)(o0 + i) * MTOT + eb + (te << 3);
        stY4(&Y1[base],     make_float4(acc[0][i], acc[1][i], acc[2][i], acc[3][i]));
        stY4(&Y1[base + 4], make_float4(acc[4][i], acc[5][i], acc[6][i], acc[7][i]));
    }
#pragma unroll
    for (int i = 0; i < 4; ++i) { s1v[i] = segsum16(s1v[i]); s2v[i] = segsum16(s2v[i]); }
    if ((t & 15) == 15) {
#pragma unroll
        for (int i = 0; i < 4; ++i) { bsm[o0 + i] = s1v[i]; bqm[o0 + i] = s2v[i]; }
    }
    __syncthreads();
    if (t < 64) atomicAdd(&gs[t], bsm[t]);
    else if (t < 128) atomicAdd(&gq[t - 64], bqm[t - 64]);
}

// ------ conv2s: tiled GEMM + in-block BN1 finalize. thread: 8 elem x 8 out ------
template <typename YT>
__global__ __launch_bounds__(256) void conv2s_kernel(
    const YT* __restrict__ Y1, const float* __restrict__ w2, const float* __restrict__ b2,
    const float* __restrict__ gsp, const float* __restrict__ gqp,
    const float* __restrict__ g, const float* __restrict__ bb,
    float* __restrict__ gs, float* __restrict__ gq,
    float* __restrict__ Mx, float* __restrict__ Mn) {
    __shared__ float At[64][128];
    __shared__ float Wt[64][128];
    __shared__ float bnsc[64], bnsh[64];
    __shared__ float bsm[128], bqm[128];
    __shared__ float mxs[4][128], mns[4][128];
    const int t = threadIdx.x;
    const int eb = blockIdx.x << 7;
    if (t < 64) {
        const float inv = 1.f / (float)MTOT;
        float mean = gsp[t] * inv;
        float var = gqp[t] * inv - mean * mean;
        float r = g[t] / sqrtf(var + 1e-5f);
        bnsc[t] = r; bnsh[t] = bb[t] - mean * r;
    }
    for (int i = t; i < 8192; i += 256) {
        int o = i & 127, c = i >> 7;
        Wt[c][o] = w2[o * 64 + c];
    }
    __syncthreads();
#pragma unroll
    for (int r = 0; r < 8; ++r) {
        int L = (r << 8) + t;
        int c = L >> 5, col = (L & 31) << 2;
        float4 y = ldY4(&Y1[(size_t)c * MTOT + eb + col]);
        float sx = bnsc[c], hx = bnsh[c];
        At[c][col]     = fmaxf(sx * y.x + hx, 0.f);
        At[c][col + 1] = fmaxf(sx * y.y + hx, 0.f);
        At[c][col + 2] = fmaxf(sx * y.z + hx, 0.f);
        At[c][col + 3] = fmaxf(sx * y.w + hx, 0.f);
    }
    __syncthreads();
    const int te = t & 15, to = t >> 4;
    float acc[8][8];
#pragma unroll
    for (int j = 0; j < 8; ++j)
#pragma unroll
        for (int i = 0; i < 8; ++i) acc[j][i] = 0.f;
#pragma unroll 2
    for (int c = 0; c < 64; ++c) {
        const float4 a0 = *(const float4*)&At[c][te << 3];
        const float4 a1 = *(const float4*)&At[c][(te << 3) + 4];
        const float4 wa = *(const float4*)&Wt[c][to << 3];
        const float4 wb = *(const float4*)&Wt[c][(to << 3) + 4];
        const float av[8] = {a0.x, a0.y, a0.z, a0.w, a1.x, a1.y, a1.z, a1.w};
        const float wvv[8] = {wa.x, wa.y, wa.z, wa.w, wb.x, wb.y, wb.z, wb.w};
#pragma unroll
        for (int j = 0; j < 8; ++j)
#pragma unroll
            for (int i = 0; i < 8; ++i) acc[j][i] += av[j] * wvv[i];
    }
    const int o0 = to << 3;
    float s1v[8], s2v[8], mxv[8], mnv[8];
#pragma unroll
    for (int i = 0; i < 8; ++i) {
        const float bi = b2[o0 + i];
        float ss = 0.f, qq = 0.f;
        float mx = -3.4e38f, mn = 3.4e38f;
#pragma unroll
        for (int j = 0; j < 8; ++j) {
            float v = acc[j][i] + bi;
            ss += v; qq += v * v;
            mx = fmaxf(mx, v); mn = fminf(mn, v);
        }
        s1v[i] = ss; s2v[i] = qq; mxv[i] = mx; mnv[i] = mn;
    }
#pragma unroll
    for (int i = 0; i < 8; ++i) {
        s1v[i] = segsum16(s1v[i]); s2v[i] = segsum16(s2v[i]);
        mxv[i] = quadmax(mxv[i]);  mnv[i] = quadmin(mnv[i]);
    }
    if ((t & 15) == 15) {
#pragma unroll
        for (int i = 0; i < 8; ++i) { bsm[o0 + i] = s1v[i]; bqm[o0 + i] = s2v[i]; }
    }
    if ((t & 3) == 0) {
        const int srow = (t & 15) >> 2;
#pragma unroll
        for (int i = 0; i < 8; ++i) { mxs[srow][o0 + i] = mxv[i]; mns[srow][o0 + i] = mnv[i]; }
    }
    __syncthreads();
    if (t < 128) atomicAdd(&gs[t], bsm[t]);
    else atomicAdd(&gq[t - 128], bqm[t - 128]);
    const int sidx0 = blockIdx.x << 2;
    for (int i = t; i < 512; i += 256) {
        int row = i >> 7, o = i & 127;
        Mx[(size_t)(sidx0 + row) * 128 + o] = mxs[row][o];
        Mn[(size_t)(sidx0 + row) * 128 + o] = mns[row][o];
    }
}

// ------- final2: in-block BN2 finalize + relu on extreme over k + transpose -----
__global__ __launch_bounds__(256) void final2_kernel(
    const float* __restrict__ Mx, const float* __restrict__ Mn,
    const float* __restrict__ gsp, const float* __restrict__ gqp,
    const float* __restrict__ g, const float* __restrict__ bb,
    float* __restrict__ out) {
    __shared__ float T[128][65];
    __shared__ float bnsc[128], bnsh[128];
    const int t = threadIdx.x;
    if (t < 128) {
        const float inv = 1.f / (float)MTOT;
        float mean = gsp[t] * inv;
        float var = gqp[t] * inv - mean * mean;
        float r = g[t] / sqrtf(var + 1e-5f);
        bnsc[t] = r; bnsh[t] = bb[t] - mean * r;
    }
    __syncthreads();
    const int b = blockIdx.x >> 4, s0 = (blockIdx.x & 15) << 6;
    for (int i = t; i < 8192; i += 256) {
        int r = i >> 7, o = i & 127;
        size_t src = ((size_t)(b << 10) + s0 + r) * 128 + o;
        float a = bnsc[o];
        float m = (a >= 0.f) ? Mx[src] : Mn[src];
        T[o][r] = fmaxf(a * m + bnsh[o], 0.f);
    }
    __syncthreads();
    float* np = out + NEWP_OFF;
    for (int i = t; i < 8192; i += 256) {
        int o = i >> 6, r = i & 63;
        np[((size_t)(b << 7) + o) * 1024 + s0 + r] = T[o][r];
    }
}

extern "C" void kernel_launch(void* const* d_in, const int* in_sizes, int n_in,
                              void* d_out, int out_size, void* d_ws, size_t ws_size,
                              hipStream_t stream) {
    const float* xyz = (const float*)d_in[0];
    const float* points = (const float*)d_in[1];
    const float* w0 = (const float*)d_in[2];
    const float* b0 = (const float*)d_in[3];
    const float* g0 = (const float*)d_in[4];
    const float* bb0 = (const float*)d_in[5];
    const float* w1 = (const float*)d_in[6];
    const float* b1 = (const float*)d_in[7];
    const float* g1 = (const float*)d_in[8];
    const float* bb1 = (const float*)d_in[9];
    const float* w2 = (const float*)d_in[10];
    const float* b2 = (const float*)d_in[11];
    const float* g2 = (const float*)d_in[12];
    const float* bb2 = (const float*)d_in[13];
    float* out = (float*)d_out;
    char* ws = (char*)d_ws;

    int* knn = (int*)(ws);                               // 2 MiB
    int* fps = (int*)(ws + (2u << 20));                  // 64 KiB
    float* stats = (float*)(ws + (2u << 20) + (1u << 16));
    float *gs0 = stats, *gq0 = stats + 64, *gs1 = stats + 128, *gq1 = stats + 192;
    float *gs2 = stats + 256, *gq2 = stats + 384;
    float4* cpt4 = (float4*)(ws + (3ull << 20));         // 1 MiB packed coords
    float* Mx = (float*)(ws + (4ull << 20));             // 8 MiB
    float* Mn = (float*)(ws + (12ull << 20));            // 8 MiB
    const size_t yoff = 20ull << 20;
    const size_t ybytes_f32 = (size_t)MTOT * 64 * 4;
    const bool f32p = ws_size >= yoff + 2 * ybytes_f32;

    (void)hipMemsetAsync(stats, 0, 512 * sizeof(float), stream);
    pack_kernel<<<NB * NN / 256, 256, 0, stream>>>(xyz, cpt4);
    fps_kernel<<<NB, 256, 0, stream>>>(xyz, fps);
    knn_kernel<<<NB * 32, 256, 0, stream>>>(cpt4, fps, knn, out);

    if (f32p) {
        float* Y0 = (float*)(ws + yoff);
        float* Y1 = Y0 + (size_t)MTOT * 64;
        conv0_kernel<float><<<4096, 256, 0, stream>>>(xyz, points, out, knn, w0, b0, Y0, gs0, gq0);
        conv1_kernel<float><<<4096, 256, 0, stream>>>(Y0, w1, b1, gs0, gq0, g0, bb0, Y1, gs1, gq1);
        conv2s_kernel<float><<<4096, 256, 0, stream>>>(Y1, w2, b2, gs1, gq1, g1, bb1, gs2, gq2, Mx, Mn);
    } else {
        __hip_bfloat16* Y0 = (__hip_bfloat16*)(ws + yoff);
        __hip_bfloat16* Y1 = Y0 + (size_t)MTOT * 64;
        conv0_kernel<__hip_bfloat16><<<4096, 256, 0, stream>>>(xyz, points, out, knn, w0, b0, Y0, gs0, gq0);
        conv1_kernel<__hip_bfloat16><<<4096, 256, 0, stream>>>(Y0, w1, b1, gs0, gq0, g0, bb0, Y1, gs1, gq1);
        conv2s_kernel<__hip_bfloat16><<<4096, 256, 0, stream>>>(Y1, w2, b2, gs1, gq1, g1, bb1, gs2, gq2, Mx, Mn);
    }
    final2_kernel<<<256, 256, 0, stream>>>(Mx, Mn, gs2, gq2, g2, bb2, out);
}

// Round 18
// 1119.441 us; speedup vs baseline: 1.9574x; 1.1573x over previous
//
#include <hip/hip_runtime.h>
#include <hip/hip_bf16.h>

#define NB 16
#define NN 4096
#define NS 1024
#define NK 32
#define CF 64
#define CIN 67
#define MTOT 524288          // NB*NS*NK
#define NEWP_OFF 49152       // NB*NS*3

__device__ inline void stY(float* p, float v) { *p = v; }
__device__ inline void stY(__hip_bfloat16* p, float v) { *p = __float2bfloat16(v); }
__device__ inline float ldY(const float* p) { return *p; }
__device__ inline float ldY(const __hip_bfloat16* p) { return __bfloat162float(*p); }
__device__ inline float4 ldY4(const float* p) { return *(const float4*)p; }
__device__ inline float4 ldY4(const __hip_bfloat16* p) {
    return make_float4(ldY(p), ldY(p + 1), ldY(p + 2), ldY(p + 3));
}
__device__ inline void stY4(float* p, float4 v) { *(float4*)p = v; }
__device__ inline void stY4(__hip_bfloat16* p, float4 v) {
    stY(p, v.x); stY(p + 1, v.y); stY(p + 2, v.z); stY(p + 3, v.w);
}

// ---- DPP reduce helpers (ctrl must be ICE -> template) -------------------------
template <int CTRL>
__device__ inline float dppredmax(float v) {
    int j = __builtin_amdgcn_update_dpp(__float_as_int(v), __float_as_int(v),
                                        CTRL, 0xF, 0xF, false);
    return fmaxf(v, __int_as_float(j));
}
template <int CTRL>
__device__ inline float dppredmin(float v) {
    int j = __builtin_amdgcn_update_dpp(__float_as_int(v), __float_as_int(v),
                                        CTRL, 0xF, 0xF, false);
    return fminf(v, __int_as_float(j));
}
template <int CTRL>
__device__ inline float dppadd0(float v) {   // bound_ctrl=1: invalid lanes read 0
    int j = __builtin_amdgcn_update_dpp(0, __float_as_int(v), CTRL, 0xF, 0xF, true);
    return __fadd_rn(v, __int_as_float(j));
}
template <int CTRL>
__device__ inline unsigned dppminu(unsigned v) {   // mov_dpp + v_min_u32
    unsigned j = (unsigned)__builtin_amdgcn_update_dpp((int)v, (int)v, CTRL, 0xF, 0xF, false);
    return j < v ? j : v;
}
__device__ inline float wavemax_to_all(float tmax) {
    float g = tmax;
    g = dppredmax<0x111>(g);   // row_shr:1
    g = dppredmax<0x112>(g);   // row_shr:2
    g = dppredmax<0x114>(g);   // row_shr:4
    g = dppredmax<0x118>(g);   // row_shr:8
    g = dppredmax<0x142>(g);   // row_bcast15
    g = dppredmax<0x143>(g);   // row_bcast31 -> lane 63 = wave max
    return __int_as_float(__builtin_amdgcn_readlane(__float_as_int(g), 63));
}
__device__ inline unsigned waveminu_to_all(unsigned v) {
    v = dppminu<0x111>(v); v = dppminu<0x112>(v); v = dppminu<0x114>(v);
    v = dppminu<0x118>(v); v = dppminu<0x142>(v); v = dppminu<0x143>(v);
    return (unsigned)__builtin_amdgcn_readlane((int)v, 63);
}
__device__ inline float segsum16(float v) {    // lanes 15,31,47,63 hold 16-seg sum
    v = dppadd0<0x111>(v); v = dppadd0<0x112>(v);
    v = dppadd0<0x114>(v); v = dppadd0<0x118>(v);
    return v;
}
__device__ inline float segsum32(float v) {    // lanes 31,63 hold 32-seg sum
    v = segsum16(v); v = dppadd0<0x142>(v);
    return v;
}
__device__ inline float quadmax(float v) {     // all 4 lanes of quad hold max
    v = dppredmax<0xB1>(v); v = dppredmax<0x4E>(v);
    return v;
}
__device__ inline float quadmin(float v) {
    v = dppredmin<0xB1>(v); v = dppredmin<0x4E>(v);
    return v;
}

// -------- FPS (round-6 proven, 594us): cpt LDS + all-DPP max + u64 part --------
__global__ __launch_bounds__(256) void fps_kernel(const float* __restrict__ xyz,
                                                  int* __restrict__ fps_idx) {
    __shared__ float4 cpt[NN];                  // 64 KiB packed coords
    __shared__ unsigned long long part[2][4];
    const int b = blockIdx.x, t = threadIdx.x;
    const float4* src = (const float4*)(xyz + (size_t)b * NN * 3);
    float px[16], py[16], pz[16], dist[16];
#pragma unroll
    for (int j = 0; j < 4; ++j) {
        float4 A = src[t * 12 + 3 * j], B4 = src[t * 12 + 3 * j + 1], C4 = src[t * 12 + 3 * j + 2];
        px[4 * j + 0] = A.x;  py[4 * j + 0] = A.y;  pz[4 * j + 0] = A.z;
        px[4 * j + 1] = A.w;  py[4 * j + 1] = B4.x; pz[4 * j + 1] = B4.y;
        px[4 * j + 2] = B4.z; py[4 * j + 2] = B4.w; pz[4 * j + 2] = C4.x;
        px[4 * j + 3] = C4.y; py[4 * j + 3] = C4.z; pz[4 * j + 3] = C4.w;
    }
#pragma unroll
    for (int i = 0; i < 16; ++i) {
        dist[i] = 1e10f;
        cpt[16 * t + i] = make_float4(px[i], py[i], pz[i], 0.f);
    }
    __syncthreads();
    int cur = 0;
    float4 c = cpt[0];
    const int wv = t >> 6;
    for (int s = 0; s < NS; ++s) {
        if (t == 0) fps_idx[(b << 10) + s] = cur;
#pragma unroll
        for (int i = 0; i < 16; ++i) {
            float dx = __fsub_rn(px[i], c.x), dy = __fsub_rn(py[i], c.y), dz = __fsub_rn(pz[i], c.z);
            float d = __fadd_rn(__fadd_rn(__fmul_rn(dx, dx), __fmul_rn(dy, dy)), __fmul_rn(dz, dz));
            dist[i] = fminf(dist[i], d);
        }
        float m0 = fmaxf(dist[0], dist[1]),   m1 = fmaxf(dist[2], dist[3]);
        float m2 = fmaxf(dist[4], dist[5]),   m3 = fmaxf(dist[6], dist[7]);
        float m4 = fmaxf(dist[8], dist[9]),   m5 = fmaxf(dist[10], dist[11]);
        float m6 = fmaxf(dist[12], dist[13]), m7 = fmaxf(dist[14], dist[15]);
        m0 = fmaxf(m0, m1); m2 = fmaxf(m2, m3); m4 = fmaxf(m4, m5); m6 = fmaxf(m6, m7);
        m0 = fmaxf(m0, m2); m4 = fmaxf(m4, m6);
        const float tmax = fmaxf(m0, m4);
        int mi = 15;
#pragma unroll
        for (int i = 14; i >= 0; --i) mi = (dist[i] == tmax) ? i : mi;
        const float gmax = wavemax_to_all(tmax);
        unsigned long long mask = __ballot(tmax == gmax);
        int ldr = __ffsll(mask) - 1;
        int widx = __builtin_amdgcn_readlane(16 * t + mi, ldr);
        if ((t & 63) == 0) {
            part[s & 1][wv] =
                ((unsigned long long)__float_as_uint(gmax) << 32) | (unsigned)(4095 - widx);
        }
        __syncthreads();
        unsigned long long k0 = part[s & 1][0], k1 = part[s & 1][1];
        unsigned long long k2 = part[s & 1][2], k3 = part[s & 1][3];
        unsigned long long ka = k0 > k1 ? k0 : k1, kb = k2 > k3 ? k2 : k3;
        unsigned long long k = ka > kb ? ka : kb;
        cur = 4095 - (int)(unsigned)(k & 0xffffffffu);
        c = cpt[cur];
    }
}

// ---- pack: {x,y,z,|p|^2} into global float4 (same rn formula as before) --------
__global__ __launch_bounds__(256) void pack_kernel(const float* __restrict__ xyz,
                                                   float4* __restrict__ cp) {
    const int i = blockIdx.x * 256 + threadIdx.x;   // 0 .. NB*NN-1
    const float* xr = xyz + (size_t)i * 3;
    float x = xr[0], y = xr[1], z = xr[2];
    float pn = __fadd_rn(__fadd_rn(__fmul_rn(x, x), __fmul_rn(y, y)), __fmul_rn(z, z));
    cp[i] = make_float4(x, y, z, pn);
}

// ---- kNN v5: ONE wave per centroid (4096 blocks -> 16 blocks/CU schedulable) ---
__global__ __launch_bounds__(256, 4) void knn_kernel(const float4* __restrict__ cpt4,
                                                     const int* __restrict__ fps_idx,
                                                     int* __restrict__ knn,
                                                     float* __restrict__ out) {
    const int t = threadIdx.x;
    const int lane = t & 63, wv = t >> 6;
    const int cid = (blockIdx.x << 2) + wv;        // 0 .. NB*NS-1
    const int b = cid >> 10, s = cid & 1023;
    const float4* __restrict__ cpt = cpt4 + ((size_t)b << 12);
    const int ci = fps_idx[cid];
    const float4 cq = cpt[ci];
    const float cx = cq.x, cy = cq.y, cz = cq.z, cn = cq.w;
    if (lane < 3) out[(size_t)cid * 3 + lane] = (lane == 0) ? cx : (lane == 1 ? cy : cz);
    unsigned long long m1 = ~0ULL, m2 = ~0ULL, m3 = ~0ULL;
#pragma unroll 8
    for (int i = 0; i < 64; ++i) {
        int p = lane + (i << 6);
        float4 q = cpt[p];
        float dot = __fadd_rn(__fadd_rn(__fmul_rn(cx, q.x), __fmul_rn(cy, q.y)),
                              __fmul_rn(cz, q.z));
        float d2 = __fsub_rn(__fadd_rn(cn, q.w), __fmul_rn(2.0f, dot));
        unsigned u = __float_as_uint(d2);
        unsigned enc = u ^ ((unsigned)((int)u >> 31) | 0x80000000u);
        unsigned long long key = ((unsigned long long)enc << 32) | (unsigned)p;
        if (key < m3) {
            if (key < m1)      { m3 = m2; m2 = m1; m1 = key; }
            else if (key < m2) { m3 = m2; m2 = key; }
            else               { m3 = key; }
        }
    }
    unsigned myidx = 0;
    for (int j = 0; j < 32; ++j) {
        const unsigned m1e = (unsigned)(m1 >> 32);
        const unsigned ge = waveminu_to_all(m1e);
        const unsigned long long mask = __ballot(m1e == ge);
        unsigned cp;
        if (__popcll(mask) == 1) {
            cp = (unsigned)__builtin_amdgcn_readlane((int)(unsigned)m1,
                                                     __ffsll(mask) - 1);
        } else {
            unsigned cand = (m1e == ge) ? (unsigned)m1 : 0xFFFFFFFFu;
            cp = waveminu_to_all(cand);
        }
        if (lane == j) myidx = cp;
        const unsigned long long vmin = ((unsigned long long)ge << 32) | cp;
        if (m1 == vmin) {
            m1 = m2; m2 = m3; m3 = ~0ULL;
            if (m1 == ~0ULL) {
#pragma unroll 8
                for (int i = 0; i < 64; ++i) {
                    int p = lane + (i << 6);
                    float4 q = cpt[p];
                    float dot = __fadd_rn(__fadd_rn(__fmul_rn(cx, q.x), __fmul_rn(cy, q.y)),
                                          __fmul_rn(cz, q.z));
                    float d2 = __fsub_rn(__fadd_rn(cn, q.w), __fmul_rn(2.0f, dot));
                    unsigned u = __float_as_uint(d2);
                    unsigned enc = u ^ ((unsigned)((int)u >> 31) | 0x80000000u);
                    unsigned long long key = ((unsigned long long)enc << 32) | (unsigned)p;
                    if (key > vmin && key < m3) {
                        if (key < m1)      { m3 = m2; m2 = m1; m1 = key; }
                        else if (key < m2) { m3 = m2; m2 = key; }
                        else               { m3 = key; }
                    }
                }
            }
        }
    }
    if (lane < 32) knn[(cid << 5) + lane] = (int)myidx;
}

// ------ conv0: tiled GEMM. TILE_E=128, C=67, O=64. thread: 4 elem x 8 out -------
template <typename YT>
__global__ __launch_bounds__(256) void conv0_kernel(
    const float* __restrict__ xyz, const float* __restrict__ points,
    const float* __restrict__ out_xyz, const int* __restrict__ knn,
    const float* __restrict__ w0, const float* __restrict__ b0,
    YT* __restrict__ Y0, float* __restrict__ gs, float* __restrict__ gq) {
    __shared__ float Ht[CIN][128];
    __shared__ float Wt[CIN][64];
    __shared__ float bsm[64], bqm[64];
    const int t = threadIdx.x;
    const int eb = blockIdx.x << 7;
    for (int i = t; i < CIN * 64; i += 256) {
        int c = i >> 6, o = i & 63;
        Wt[c][o] = w0[o * CIN + c];
    }
    {
        const int le = t >> 1, part = t & 1;
        const int e = eb + le;
        const int b = e >> 15, s = (e >> 5) & 1023;
        const int pidx = knn[e];
        const float4* pr = (const float4*)(points + (((size_t)(b << 12) + pidx) << 6)) + (part << 3);
        if (part == 0) {
            const float* xr = xyz + ((size_t)(b << 12) + pidx) * 3;
            const float* cr = out_xyz + ((size_t)(b << 10) + s) * 3;
            Ht[0][le] = xr[0] - cr[0];
            Ht[1][le] = xr[1] - cr[1];
            Ht[2][le] = xr[2] - cr[2];
        }
#pragma unroll
        for (int q = 0; q < 8; ++q) {
            float4 v = pr[q];
            int c = 3 + (part << 5) + (q << 2);
            Ht[c][le] = v.x; Ht[c + 1][le] = v.y; Ht[c + 2][le] = v.z; Ht[c + 3][le] = v.w;
        }
    }
    __syncthreads();
    const int te = t & 31, to = t >> 5;
    float acc[4][8];
#pragma unroll
    for (int j = 0; j < 4; ++j)
#pragma unroll
        for (int i = 0; i < 8; ++i) acc[j][i] = 0.f;
#pragma unroll 2
    for (int c = 0; c < CIN; ++c) {
        const float4 a0 = *(const float4*)&Ht[c][te << 2];
        const float4 wa = *(const float4*)&Wt[c][to << 3];
        const float4 wb = *(const float4*)&Wt[c][(to << 3) + 4];
        const float av[4] = {a0.x, a0.y, a0.z, a0.w};
        const float wvv[8] = {wa.x, wa.y, wa.z, wa.w, wb.x, wb.y, wb.z, wb.w};
#pragma unroll
        for (int j = 0; j < 4; ++j)
#pragma unroll
            for (int i = 0; i < 8; ++i) acc[j][i] += av[j] * wvv[i];
    }
    const int o0 = to << 3;
    float s1v[8], s2v[8];
#pragma unroll
    for (int i = 0; i < 8; ++i) {
        const float bi = b0[o0 + i];
        float ss = 0.f, qq = 0.f;
#pragma unroll
        for (int j = 0; j < 4; ++j) {
            float v = acc[j][i] + bi;
            acc[j][i] = v;
            ss += v; qq += v * v;
        }
        s1v[i] = ss; s2v[i] = qq;
    }
#pragma unroll
    for (int i = 0; i < 8; ++i) {
        const size_t base = (size_t)(o0 + i) * MTOT + eb + (te << 2);
        stY4(&Y0[base], make_float4(acc[0][i], acc[1][i], acc[2][i], acc[3][i]));
    }
#pragma unroll
    for (int i = 0; i < 8; ++i) { s1v[i] = segsum32(s1v[i]); s2v[i] = segsum32(s2v[i]); }
    if ((t & 31) == 31) {
#pragma unroll
        for (int i = 0; i < 8; ++i) { bsm[o0 + i] = s1v[i]; bqm[o0 + i] = s2v[i]; }
    }
    __syncthreads();
    if (t < 64) atomicAdd(&gs[t], bsm[t]);
    else if (t < 128) atomicAdd(&gq[t - 64], bqm[t - 64]);
}

// ------ conv1: tiled GEMM + in-block BN0 finalize. thread: 8 elem x 4 out -------
template <typename YT>
__global__ __launch_bounds__(256) void conv1_kernel(
    const YT* __restrict__ Y0, const float* __restrict__ w1, const float* __restrict__ b1,
    const float* __restrict__ gsp, const float* __restrict__ gqp,
    const float* __restrict__ g, const float* __restrict__ bb,
    YT* __restrict__ Y1, float* __restrict__ gs, float* __restrict__ gq) {
    __shared__ float At[64][128];
    __shared__ float Wt[64][64];
    __shared__ float bnsc[64], bnsh[64];
    __shared__ float bsm[64], bqm[64];
    const int t = threadIdx.x;
    const int eb = blockIdx.x << 7;
    if (t < 64) {
        const float inv = 1.f / (float)MTOT;
        float mean = gsp[t] * inv;
        float var = gqp[t] * inv - mean * mean;
        float r = g[t] / sqrtf(var + 1e-5f);
        bnsc[t] = r; bnsh[t] = bb[t] - mean * r;
    }
    for (int i = t; i < 4096; i += 256) {
        int c = i >> 6, o = i & 63;
        Wt[c][o] = w1[o * 64 + c];
    }
    __syncthreads();
#pragma unroll
    for (int r = 0; r < 8; ++r) {
        int L = (r << 8) + t;                 // float4 id
        int c = L >> 5, col = (L & 31) << 2;
        float4 y = ldY4(&Y0[(size_t)c * MTOT + eb + col]);
        float sx = bnsc[c], hx = bnsh[c];
        At[c][col]     = fmaxf(sx * y.x + hx, 0.f);
        At[c][col + 1] = fmaxf(sx * y.y + hx, 0.f);
        At[c][col + 2] = fmaxf(sx * y.z + hx, 0.f);
        At[c][col + 3] = fmaxf(sx * y.w + hx, 0.f);
    }
    __syncthreads();
    const int te = t & 15, to = t >> 4;
    float acc[8][4];
#pragma unroll
    for (int j = 0; j < 8; ++j)
#pragma unroll
        for (int i = 0; i < 4; ++i) acc[j][i] = 0.f;
#pragma unroll 2
    for (int c = 0; c < 64; ++c) {
        const float4 a0 = *(const float4*)&At[c][te << 3];
        const float4 a1 = *(const float4*)&At[c][(te << 3) + 4];
        const float4 wa = *(const float4*)&Wt[c][to << 2];
        const float av[8] = {a0.x, a0.y, a0.z, a0.w, a1.x, a1.y, a1.z, a1.w};
        const float wvv[4] = {wa.x, wa.y, wa.z, wa.w};
#pragma unroll
        for (int j = 0; j < 8; ++j)
#pragma unroll
            for (int i = 0; i < 4; ++i) acc[j][i] += av[j] * wvv[i];
    }
    const int o0 = to << 2;
    float s1v[4], s2v[4];
#pragma unroll
    for (int i = 0; i < 4; ++i) {
        const float bi = b1[o0 + i];
        float ss = 0.f, qq = 0.f;
#pragma unroll
        for (int j = 0; j < 8; ++j) {
            float v = acc[j][i] + bi;
            acc[j][i] = v;
            ss += v; qq += v * v;
        }
        s1v[i] = ss; s2v[i] = qq;
    }
#pragma unroll
    for (int i = 0; i < 4; ++i) {
        const size_t base = (size_t)(o0 + i) * MTOT + eb + (te << 3);
        stY4(&Y1[base],     make_float4(acc[0][i], acc[1][i], acc[2][i], acc[3][i]));
        stY4(&Y1[base + 4], make_float4(acc[4][i], acc[5][i], acc[6][i], acc[7][i]));
    }
#pragma unroll
    for (int i = 0; i < 4; ++i) { s1v[i] = segsum16(s1v[i]); s2v[i] = segsum16(s2v[i]); }
    if ((t & 15) == 15) {
#pragma unroll
        for (int i = 0; i < 4; ++i) { bsm[o0 + i] = s1v[i]; bqm[o0 + i] = s2v[i]; }
    }
    __syncthreads();
    if (t < 64) atomicAdd(&gs[t], bsm[t]);
    else if (t < 128) atomicAdd(&gq[t - 64], bqm[t - 64]);
}

// ------ conv2s: tiled GEMM + in-block BN1 finalize. thread: 8 elem x 8 out ------
template <typename YT>
__global__ __launch_bounds__(256) void conv2s_kernel(
    const YT* __restrict__ Y1, const float* __restrict__ w2, const float* __restrict__ b2,
    const float* __restrict__ gsp, const float* __restrict__ gqp,
    const float* __restrict__ g, const float* __restrict__ bb,
    float* __restrict__ gs, float* __restrict__ gq,
    float* __restrict__ Mx, float* __restrict__ Mn) {
    __shared__ float At[64][128];
    __shared__ float Wt[64][128];
    __shared__ float bnsc[64], bnsh[64];
    __shared__ float bsm[128], bqm[128];
    __shared__ float mxs[4][128], mns[4][128];
    const int t = threadIdx.x;
    const int eb = blockIdx.x << 7;
    if (t < 64) {
        const float inv = 1.f / (float)MTOT;
        float mean = gsp[t] * inv;
        float var = gqp[t] * inv - mean * mean;
        float r = g[t] / sqrtf(var + 1e-5f);
        bnsc[t] = r; bnsh[t] = bb[t] - mean * r;
    }
    for (int i = t; i < 8192; i += 256) {
        int o = i & 127, c = i >> 7;
        Wt[c][o] = w2[o * 64 + c];
    }
    __syncthreads();
#pragma unroll
    for (int r = 0; r < 8; ++r) {
        int L = (r << 8) + t;
        int c = L >> 5, col = (L & 31) << 2;
        float4 y = ldY4(&Y1[(size_t)c * MTOT + eb + col]);
        float sx = bnsc[c], hx = bnsh[c];
        At[c][col]     = fmaxf(sx * y.x + hx, 0.f);
        At[c][col + 1] = fmaxf(sx * y.y + hx, 0.f);
        At[c][col + 2] = fmaxf(sx * y.z + hx, 0.f);
        At[c][col + 3] = fmaxf(sx * y.w + hx, 0.f);
    }
    __syncthreads();
    const int te = t & 15, to = t >> 4;
    float acc[8][8];
#pragma unroll
    for (int j = 0; j < 8; ++j)
#pragma unroll
        for (int i = 0; i < 8; ++i) acc[j][i] = 0.f;
#pragma unroll 2
    for (int c = 0; c < 64; ++c) {
        const float4 a0 = *(const float4*)&At[c][te << 3];
        const float4 a1 = *(const float4*)&At[c][(te << 3) + 4];
        const float4 wa = *(const float4*)&Wt[c][to << 3];
        const float4 wb = *(const float4*)&Wt[c][(to << 3) + 4];
        const float av[8] = {a0.x, a0.y, a0.z, a0.w, a1.x, a1.y, a1.z, a1.w};
        const float wvv[8] = {wa.x, wa.y, wa.z, wa.w, wb.x, wb.y, wb.z, wb.w};
#pragma unroll
        for (int j = 0; j < 8; ++j)
#pragma unroll
            for (int i = 0; i < 8; ++i) acc[j][i] += av[j] * wvv[i];
    }
    const int o0 = to << 3;
    float s1v[8], s2v[8], mxv[8], mnv[8];
#pragma unroll
    for (int i = 0; i < 8; ++i) {
        const float bi = b2[o0 + i];
        float ss = 0.f, qq = 0.f;
        float mx = -3.4e38f, mn = 3.4e38f;
#pragma unroll
        for (int j = 0; j < 8; ++j) {
            float v = acc[j][i] + bi;
            ss += v; qq += v * v;
            mx = fmaxf(mx, v); mn = fminf(mn, v);
        }
        s1v[i] = ss; s2v[i] = qq; mxv[i] = mx; mnv[i] = mn;
    }
#pragma unroll
    for (int i = 0; i < 8; ++i) {
        s1v[i] = segsum16(s1v[i]); s2v[i] = segsum16(s2v[i]);
        mxv[i] = quadmax(mxv[i]);  mnv[i] = quadmin(mnv[i]);
    }
    if ((t & 15) == 15) {
#pragma unroll
        for (int i = 0; i < 8; ++i) { bsm[o0 + i] = s1v[i]; bqm[o0 + i] = s2v[i]; }
    }
    if ((t & 3) == 0) {
        const int srow = (t & 15) >> 2;
#pragma unroll
        for (int i = 0; i < 8; ++i) { mxs[srow][o0 + i] = mxv[i]; mns[srow][o0 + i] = mnv[i]; }
    }
    __syncthreads();
    if (t < 128) atomicAdd(&gs[t], bsm[t]);
    else atomicAdd(&gq[t - 128], bqm[t - 128]);
    const int sidx0 = blockIdx.x << 2;
    for (int i = t; i < 512; i += 256) {
        int row = i >> 7, o = i & 127;
        Mx[(size_t)(sidx0 + row) * 128 + o] = mxs[row][o];
        Mn[(size_t)(sidx0 + row) * 128 + o] = mns[row][o];
    }
}

// ------- final2: in-block BN2 finalize + relu on extreme over k + transpose -----
__global__ __launch_bounds__(256) void final2_kernel(
    const float* __restrict__ Mx, const float* __restrict__ Mn,
    const float* __restrict__ gsp, const float* __restrict__ gqp,
    const float* __restrict__ g, const float* __restrict__ bb,
    float* __restrict__ out) {
    __shared__ float T[128][65];
    __shared__ float bnsc[128], bnsh[128];
    const int t = threadIdx.x;
    if (t < 128) {
        const float inv = 1.f / (float)MTOT;
        float mean = gsp[t] * inv;
        float var = gqp[t] * inv - mean * mean;
        float r = g[t] / sqrtf(var + 1e-5f);
        bnsc[t] = r; bnsh[t] = bb[t] - mean * r;
    }
    __syncthreads();
    const int b = blockIdx.x >> 4, s0 = (blockIdx.x & 15) << 6;
    for (int i = t; i < 8192; i += 256) {
        int r = i >> 7, o = i & 127;
        size_t src = ((size_t)(b << 10) + s0 + r) * 128 + o;
        float a = bnsc[o];
        float m = (a >= 0.f) ? Mx[src] : Mn[src];
        T[o][r] = fmaxf(a * m + bnsh[o], 0.f);
    }
    __syncthreads();
    float* np = out + NEWP_OFF;
    for (int i = t; i < 8192; i += 256) {
        int o = i >> 6, r = i & 63;
        np[((size_t)(b << 7) + o) * 1024 + s0 + r] = T[o][r];
    }
}

extern "C" void kernel_launch(void* const* d_in, const int* in_sizes, int n_in,
                              void* d_out, int out_size, void* d_ws, size_t ws_size,
                              hipStream_t stream) {
    const float* xyz = (const float*)d_in[0];
    const float* points = (const float*)d_in[1];
    const float* w0 = (const float*)d_in[2];
    const float* b0 = (const float*)d_in[3];
    const float* g0 = (const float*)d_in[4];
    const float* bb0 = (const float*)d_in[5];
    const float* w1 = (const float*)d_in[6];
    const float* b1 = (const float*)d_in[7];
    const float* g1 = (const float*)d_in[8];
    const float* bb1 = (const float*)d_in[9];
    const float* w2 = (const float*)d_in[10];
    const float* b2 = (const float*)d_in[11];
    const float* g2 = (const float*)d_in[12];
    const float* bb2 = (const float*)d_in[13];
    float* out = (float*)d_out;
    char* ws = (char*)d_ws;

    int* knn = (int*)(ws);                               // 2 MiB
    int* fps = (int*)(ws + (2u << 20));                  // 64 KiB
    float* stats = (float*)(ws + (2u << 20) + (1u << 16));
    float *gs0 = stats, *gq0 = stats + 64, *gs1 = stats + 128, *gq1 = stats + 192;
    float *gs2 = stats + 256, *gq2 = stats + 384;
    float4* cpt4 = (float4*)(ws + (3ull << 20));         // 1 MiB packed coords
    float* Mx = (float*)(ws + (4ull << 20));             // 8 MiB
    float* Mn = (float*)(ws + (12ull << 20));            // 8 MiB
    const size_t yoff = 20ull << 20;
    const size_t ybytes_f32 = (size_t)MTOT * 64 * 4;
    const bool f32p = ws_size >= yoff + 2 * ybytes_f32;

    (void)hipMemsetAsync(stats, 0, 512 * sizeof(float), stream);
    pack_kernel<<<NB * NN / 256, 256, 0, stream>>>(xyz, cpt4);
    fps_kernel<<<NB, 256, 0, stream>>>(xyz, fps);
    knn_kernel<<<NB * NS / 4, 256, 0, stream>>>(cpt4, fps, knn, out);

    if (f32p) {
        float* Y0 = (float*)(ws + yoff);
        float* Y1 = Y0 + (size_t)MTOT * 64;
        conv0_kernel<float><<<4096, 256, 0, stream>>>(xyz, points, out, knn, w0, b0, Y0, gs0, gq0);
        conv1_kernel<float><<<4096, 256, 0, stream>>>(Y0, w1, b1, gs0, gq0, g0, bb0, Y1, gs1, gq1);
        conv2s_kernel<float><<<4096, 256, 0, stream>>>(Y1, w2, b2, gs1, gq1, g1, bb1, gs2, gq2, Mx, Mn);
    } else {
        __hip_bfloat16* Y0 = (__hip_bfloat16*)(ws + yoff);
        __hip_bfloat16* Y1 = Y0 + (size_t)MTOT * 64;
        conv0_kernel<__hip_bfloat16><<<4096, 256, 0, stream>>>(xyz, points, out, knn, w0, b0, Y0, gs0, gq0);
        conv1_kernel<__hip_bfloat16><<<4096, 256, 0, stream>>>(Y0, w1, b1, gs0, gq0, g0, bb0, Y1, gs1, gq1);
        conv2s_kernel<__hip_bfloat16><<<4096, 256, 0, stream>>>(Y1, w2, b2, gs1, gq1, g1, bb1, gs2, gq2, Mx, Mn);
    }
    final2_kernel<<<256, 256, 0, stream>>>(Mx, Mn, gs2, gq2, g2, bb2, out);
}